// Round 1
// baseline (7416.338 us; speedup 1.0000x reference)
//
#include <hip/hip_runtime.h>
#include <math.h>

#define VOCABSZ 50257
#define DMODEL 768
#define NHEAD 12
#define NLAYER 4
#define SEQ 1024
#define BATCH 2
#define DHEAD 64
#define DFFN 3072
#define BT (BATCH * SEQ)

// ---------------------------------------------------------------- embedding
__global__ __launch_bounds__(256) void embed_kernel(
    const int* __restrict__ tok, const float* __restrict__ emb,
    const float* __restrict__ pos, float* __restrict__ h) {
  int row = blockIdx.x;              // b*SEQ + l
  int l = row % SEQ;
  int t = tok[row];
  int tid = threadIdx.x;
#pragma unroll
  for (int j = 0; j < 3; ++j) {
    int c = tid + j * 256;
    h[(size_t)row * DMODEL + c] =
        emb[(size_t)t * DMODEL + c] + pos[(size_t)l * DMODEL + c];
  }
}

// ---------------------------------------------------------------- layernorm
__global__ __launch_bounds__(256) void ln_kernel(
    const float* __restrict__ x, const float* __restrict__ g,
    const float* __restrict__ bta, float* __restrict__ o) {
  __shared__ float red[8];
  int row = blockIdx.x;
  int tid = threadIdx.x;
  const float* xr = x + (size_t)row * DMODEL;
  float v0 = xr[tid], v1 = xr[tid + 256], v2 = xr[tid + 512];
  float s = v0 + v1 + v2;
  float sq = v0 * v0 + v1 * v1 + v2 * v2;
#pragma unroll
  for (int off = 1; off < 64; off <<= 1) {
    s += __shfl_xor(s, off);
    sq += __shfl_xor(sq, off);
  }
  int wid = tid >> 6;
  if ((tid & 63) == 0) { red[wid * 2] = s; red[wid * 2 + 1] = sq; }
  __syncthreads();
  float S = red[0] + red[2] + red[4] + red[6];
  float SQ = red[1] + red[3] + red[5] + red[7];
  float mu = S * (1.0f / DMODEL);
  float var = SQ * (1.0f / DMODEL) - mu * mu;
  float r = rsqrtf(var + 1e-5f);
  float* orow = o + (size_t)row * DMODEL;
#pragma unroll
  for (int j = 0; j < 3; ++j) {
    int c = tid + j * 256;
    float v = (j == 0) ? v0 : (j == 1) ? v1 : v2;
    orow[c] = (v - mu) * r * g[c] + bta[c];
  }
}

// ---------------------------------------------------------------- attention
// grid (SEQ, NHEAD, BATCH), block 256.  q already holds q_eff/sqrt(dh).
__global__ __launch_bounds__(256) void attn_kernel(
    const float* __restrict__ q, const float* __restrict__ k,
    const float* __restrict__ v, float* __restrict__ out) {
  __shared__ float qs[DHEAD];
  __shared__ float sc[SEQ];
  __shared__ float red[8];
  __shared__ float part[4][DHEAD];
  int b = blockIdx.z, hh = blockIdx.y, qi = blockIdx.x;
  int tid = threadIdx.x;
  const int nk = qi + 1;
  size_t base = (size_t)b * SEQ * DMODEL + (size_t)hh * DHEAD;
  if (tid < DHEAD) qs[tid] = q[base + (size_t)qi * DMODEL + tid];
  __syncthreads();
  float lmax = -1e30f;
  for (int kk = tid; kk < nk; kk += 256) {
    const float* kr = k + base + (size_t)kk * DMODEL;
    float s = 0.f;
#pragma unroll
    for (int d = 0; d < DHEAD; d += 4) {
      s += qs[d] * kr[d] + qs[d + 1] * kr[d + 1] + qs[d + 2] * kr[d + 2] +
           qs[d + 3] * kr[d + 3];
    }
    sc[kk] = s;
    lmax = fmaxf(lmax, s);
  }
  // block max
#pragma unroll
  for (int off = 1; off < 64; off <<= 1) lmax = fmaxf(lmax, __shfl_xor(lmax, off));
  if ((tid & 63) == 0) red[tid >> 6] = lmax;
  __syncthreads();
  float mx = fmaxf(fmaxf(red[0], red[1]), fmaxf(red[2], red[3]));
  __syncthreads();
  float lsum = 0.f;
  for (int kk = tid; kk < nk; kk += 256) {
    float p = __expf(sc[kk] - mx);
    sc[kk] = p;
    lsum += p;
  }
#pragma unroll
  for (int off = 1; off < 64; off <<= 1) lsum += __shfl_xor(lsum, off);
  if ((tid & 63) == 0) red[4 + (tid >> 6)] = lsum;
  __syncthreads();
  float rinv = 1.0f / (red[4] + red[5] + red[6] + red[7]);
  int d = tid & (DHEAD - 1);
  int grp = tid >> 6;
  float acc = 0.f;
  for (int kk = grp; kk < nk; kk += 4)
    acc += sc[kk] * v[base + (size_t)kk * DMODEL + d];
  part[grp][d] = acc;
  __syncthreads();
  if (grp == 0)
    out[base + (size_t)qi * DMODEL + d] =
        (part[0][d] + part[1][d] + part[2][d] + part[3][d]) * rinv;
}

// ---------------------------------------------------------------- NT GEMM
// C[m,n] = sum_k A[m,k] * B[n,k]; A: MxK row-major, B: NxK row-major.
// M must be a multiple of 64, K a multiple of 32. N guarded.
#define BM 64
#define BN 64
#define BKK 32
template <bool BIAS, bool RES, bool GELU, bool QSCALE>
__global__ __launch_bounds__(256) void gemm_nt(
    const float* __restrict__ A, const float* __restrict__ Bm,
    const float* __restrict__ bias, const int* __restrict__ tmask,
    const float* __restrict__ res, float* __restrict__ C,
    int M, int N, int K) {
  __shared__ float As[BKK][BM + 4];
  __shared__ float Bs[BKK][BN + 4];
  int n0 = blockIdx.x * BN, m0 = blockIdx.y * BM;
  int tid = threadIdx.x;
  int tx = tid & 15, ty = tid >> 4;
  int lrow = tid >> 3;        // 0..31
  int lcol = (tid & 7) * 4;   // 0,4,...,28
  float acc[4][4] = {};
  for (int k0 = 0; k0 < K; k0 += BKK) {
#pragma unroll
    for (int r = 0; r < 2; ++r) {
      int row = lrow + r * 32;
      const float4 av = *reinterpret_cast<const float4*>(
          &A[(size_t)(m0 + row) * K + k0 + lcol]);
      As[lcol + 0][row] = av.x;
      As[lcol + 1][row] = av.y;
      As[lcol + 2][row] = av.z;
      As[lcol + 3][row] = av.w;
      float4 bv = make_float4(0.f, 0.f, 0.f, 0.f);
      if (n0 + row < N)
        bv = *reinterpret_cast<const float4*>(
            &Bm[(size_t)(n0 + row) * K + k0 + lcol]);
      Bs[lcol + 0][row] = bv.x;
      Bs[lcol + 1][row] = bv.y;
      Bs[lcol + 2][row] = bv.z;
      Bs[lcol + 3][row] = bv.w;
    }
    __syncthreads();
#pragma unroll
    for (int kk = 0; kk < BKK; ++kk) {
      float4 a = *reinterpret_cast<const float4*>(&As[kk][ty * 4]);
      float4 b = *reinterpret_cast<const float4*>(&Bs[kk][tx * 4]);
      float ar[4] = {a.x, a.y, a.z, a.w};
      float br[4] = {b.x, b.y, b.z, b.w};
#pragma unroll
      for (int i = 0; i < 4; ++i)
#pragma unroll
        for (int j = 0; j < 4; ++j) acc[i][j] += ar[i] * br[j];
    }
    __syncthreads();
  }
#pragma unroll
  for (int i = 0; i < 4; ++i) {
    int m = m0 + ty * 4 + i;
#pragma unroll
    for (int j = 0; j < 4; ++j) {
      int n = n0 + tx * 4 + j;
      if (n < N) {
        float vacc = acc[i][j];
        if (QSCALE) vacc *= (1.0f - 0.5f * (float)tmask[n]) * 0.125f;
        if (BIAS) vacc += bias[n];
        if (GELU) vacc = 0.5f * vacc * (1.0f + erff(vacc * 0.70710678118f));
        if (RES) vacc += res[(size_t)m * N + n];
        C[(size_t)m * N + n] = vacc;
      }
    }
  }
}

// ---------------------------------------------------------------- launch
extern "C" void kernel_launch(void* const* d_in, const int* in_sizes, int n_in,
                              void* d_out, int out_size, void* d_ws,
                              size_t ws_size, hipStream_t stream) {
  const int* tokens = (const int*)d_in[0];
  const int* tmask = (const int*)d_in[1];
  const float* embed = (const float*)d_in[2];
  const float* pos = (const float*)d_in[3];
  const float* wq = (const float*)d_in[4];
  const float* wk = (const float*)d_in[5];
  const float* wv = (const float*)d_in[6];
  const float* wo = (const float*)d_in[7];
  const float* ln1g = (const float*)d_in[8];
  const float* ln1b = (const float*)d_in[9];
  const float* ln2g = (const float*)d_in[10];
  const float* ln2b = (const float*)d_in[11];
  const float* fw1 = (const float*)d_in[12];
  const float* fb1 = (const float*)d_in[13];
  const float* fw2 = (const float*)d_in[14];
  const float* fb2 = (const float*)d_in[15];
  const float* lnfg = (const float*)d_in[16];
  const float* lnfb = (const float*)d_in[17];

  float* h = (float*)d_ws;
  float* xn = h + (size_t)BT * DMODEL;
  float* qb = xn + (size_t)BT * DMODEL;
  float* kb = qb + (size_t)BT * DMODEL;
  float* vb = kb + (size_t)BT * DMODEL;
  float* ab = vb + (size_t)BT * DMODEL;
  float* ffb = ab + (size_t)BT * DMODEL;

  embed_kernel<<<BT, 256, 0, stream>>>(tokens, embed, pos, h);

  dim3 g768((DMODEL + 63) / 64, BT / 64);
  dim3 gff((DFFN + 63) / 64, BT / 64);
  dim3 gv((VOCABSZ + 63) / 64, BT / 64);

  for (int i = 0; i < NLAYER; ++i) {
    const float* wq_i = wq + (size_t)i * DMODEL * DMODEL;
    const float* wk_i = wk + (size_t)i * DMODEL * DMODEL;
    const float* wv_i = wv + (size_t)i * DMODEL * DMODEL;
    const float* wo_i = wo + (size_t)i * DMODEL * DMODEL;

    ln_kernel<<<BT, 256, 0, stream>>>(h, ln1g + i * DMODEL, ln1b + i * DMODEL, xn);

    gemm_nt<false, false, false, true><<<g768, 256, 0, stream>>>(
        xn, wq_i, nullptr, tmask + i * DMODEL, nullptr, qb, BT, DMODEL, DMODEL);
    gemm_nt<false, false, false, false><<<g768, 256, 0, stream>>>(
        xn, wk_i, nullptr, nullptr, nullptr, kb, BT, DMODEL, DMODEL);
    gemm_nt<false, false, false, false><<<g768, 256, 0, stream>>>(
        xn, wv_i, nullptr, nullptr, nullptr, vb, BT, DMODEL, DMODEL);

    attn_kernel<<<dim3(SEQ, NHEAD, BATCH), 256, 0, stream>>>(qb, kb, vb, ab);

    gemm_nt<false, true, false, false><<<g768, 256, 0, stream>>>(
        ab, wo_i, nullptr, nullptr, h, h, BT, DMODEL, DMODEL);

    ln_kernel<<<BT, 256, 0, stream>>>(h, ln2g + i * DMODEL, ln2b + i * DMODEL, xn);

    gemm_nt<true, false, true, false><<<gff, 256, 0, stream>>>(
        xn, fw1 + (size_t)i * DFFN * DMODEL, fb1 + i * DFFN, nullptr, nullptr,
        ffb, BT, DFFN, DMODEL);
    gemm_nt<true, true, false, false><<<g768, 256, 0, stream>>>(
        ffb, fw2 + (size_t)i * DMODEL * DFFN, fb2 + i * DMODEL, nullptr, h, h,
        BT, DMODEL, DFFN);
  }

  ln_kernel<<<BT, 256, 0, stream>>>(h, lnfg, lnfb, xn);
  gemm_nt<false, false, false, false><<<gv, 256, 0, stream>>>(
      xn, embed, nullptr, nullptr, nullptr, (float*)d_out, BT, VOCABSZ, DMODEL);
}

// Round 2
// 3712.633 us; speedup vs baseline: 1.9976x; 1.9976x over previous
//
#include <hip/hip_runtime.h>
#include <math.h>

#define VOCABSZ 50257
#define VPAD 50304
#define DMODEL 768
#define NHEAD 12
#define NLAYER 4
#define SEQ 1024
#define BATCH 2
#define DHEAD 64
#define DFFN 3072
#define BT (BATCH * SEQ)

typedef __attribute__((ext_vector_type(8))) short bf16x8;
typedef __attribute__((ext_vector_type(4))) float f32x4;

__device__ __forceinline__ ushort f2bf(float f) {
  uint u = __builtin_bit_cast(uint, f);
  u = (u + 0x7fffu + ((u >> 16) & 1u)) >> 16;
  return (ushort)u;
}

__device__ __forceinline__ void gl_lds16(const ushort* g, ushort* l) {
  __builtin_amdgcn_global_load_lds(
      (const __attribute__((address_space(1))) void*)g,
      (__attribute__((address_space(3))) void*)l, 16, 0, 0);
}

// ------------------------------------------------------------- conversions
__global__ __launch_bounds__(256) void conv4_kernel(
    const float* __restrict__ src, ushort* __restrict__ dst, int n4) {
  int i = blockIdx.x * 256 + threadIdx.x;
  if (i >= n4) return;
  float4 v = reinterpret_cast<const float4*>(src)[i];
  reinterpret_cast<ushort4*>(dst)[i] =
      make_ushort4(f2bf(v.x), f2bf(v.y), f2bf(v.z), f2bf(v.w));
}

// wq/wk/wv (NL,D,D) -> wqkv_b (NL, 3*D, D) at row offset qoff
__global__ __launch_bounds__(256) void conv_qkv_kernel(
    const float* __restrict__ src, ushort* __restrict__ dst, int qoff4) {
  const int per4 = DMODEL * DMODEL / 4;
  int i = blockIdx.x * 256 + threadIdx.x;
  if (i >= NLAYER * per4) return;
  int layer = i / per4, rem = i % per4;
  float4 v = reinterpret_cast<const float4*>(src)[i];
  reinterpret_cast<ushort4*>(dst)[(size_t)layer * (3 * per4) + qoff4 + rem] =
      make_ushort4(f2bf(v.x), f2bf(v.y), f2bf(v.z), f2bf(v.w));
}

__global__ __launch_bounds__(256) void conv_embed_kernel(
    const float* __restrict__ emb, ushort* __restrict__ dst) {
  int i = blockIdx.x * 256 + threadIdx.x;
  if (i >= VPAD * DMODEL / 4) return;
  int row = (i * 4) / DMODEL;
  ushort4 o = make_ushort4(0, 0, 0, 0);
  if (row < VOCABSZ) {
    float4 v = reinterpret_cast<const float4*>(emb)[i];
    o = make_ushort4(f2bf(v.x), f2bf(v.y), f2bf(v.z), f2bf(v.w));
  }
  reinterpret_cast<ushort4*>(dst)[i] = o;
}

// ---------------------------------------------------------------- embedding
__global__ __launch_bounds__(256) void embed_kernel(
    const int* __restrict__ tok, const float* __restrict__ emb,
    const float* __restrict__ pos, float* __restrict__ h) {
  int row = blockIdx.x;
  int l = row % SEQ;
  int t = tok[row];
  int tid = threadIdx.x;
#pragma unroll
  for (int j = 0; j < 3; ++j) {
    int c = tid + j * 256;
    h[(size_t)row * DMODEL + c] =
        emb[(size_t)t * DMODEL + c] + pos[(size_t)l * DMODEL + c];
  }
}

// ---------------------------------------------------------------- layernorm
__global__ __launch_bounds__(256) void ln_kernel(
    const float* __restrict__ x, const float* __restrict__ g,
    const float* __restrict__ bta, ushort* __restrict__ o) {
  __shared__ float red[8];
  int row = blockIdx.x;
  int tid = threadIdx.x;
  const float* xr = x + (size_t)row * DMODEL;
  float v0 = xr[tid], v1 = xr[tid + 256], v2 = xr[tid + 512];
  float s = v0 + v1 + v2;
  float sq = v0 * v0 + v1 * v1 + v2 * v2;
#pragma unroll
  for (int off = 1; off < 64; off <<= 1) {
    s += __shfl_xor(s, off);
    sq += __shfl_xor(sq, off);
  }
  int wid = tid >> 6;
  if ((tid & 63) == 0) { red[wid * 2] = s; red[wid * 2 + 1] = sq; }
  __syncthreads();
  float S = red[0] + red[2] + red[4] + red[6];
  float SQ = red[1] + red[3] + red[5] + red[7];
  float mu = S * (1.0f / DMODEL);
  float var = SQ * (1.0f / DMODEL) - mu * mu;
  float r = rsqrtf(var + 1e-5f);
  ushort* orow = o + (size_t)row * DMODEL;
#pragma unroll
  for (int j = 0; j < 3; ++j) {
    int c = tid + j * 256;
    float v = (j == 0) ? v0 : (j == 1) ? v1 : v2;
    orow[c] = f2bf((v - mu) * r * g[c] + bta[c]);
  }
}

// ---------------------------------------------------------------- attention
__global__ __launch_bounds__(256) void attn_kernel(
    const float* __restrict__ q, const float* __restrict__ k,
    const float* __restrict__ v, ushort* __restrict__ out) {
  __shared__ float qs[DHEAD];
  __shared__ float sc[SEQ];
  __shared__ float red[8];
  __shared__ float part[4][DHEAD];
  int b = blockIdx.z, hh = blockIdx.y, qi = blockIdx.x;
  int tid = threadIdx.x;
  const int nk = qi + 1;
  size_t base = (size_t)b * SEQ * DMODEL + (size_t)hh * DHEAD;
  if (tid < DHEAD) qs[tid] = q[base + (size_t)qi * DMODEL + tid];
  __syncthreads();
  float lmax = -1e30f;
  for (int kk = tid; kk < nk; kk += 256) {
    const float* kr = k + base + (size_t)kk * DMODEL;
    float s = 0.f;
#pragma unroll
    for (int d = 0; d < DHEAD; d += 4) {
      s += qs[d] * kr[d] + qs[d + 1] * kr[d + 1] + qs[d + 2] * kr[d + 2] +
           qs[d + 3] * kr[d + 3];
    }
    sc[kk] = s;
    lmax = fmaxf(lmax, s);
  }
#pragma unroll
  for (int off = 1; off < 64; off <<= 1) lmax = fmaxf(lmax, __shfl_xor(lmax, off));
  if ((tid & 63) == 0) red[tid >> 6] = lmax;
  __syncthreads();
  float mx = fmaxf(fmaxf(red[0], red[1]), fmaxf(red[2], red[3]));
  __syncthreads();
  float lsum = 0.f;
  for (int kk = tid; kk < nk; kk += 256) {
    float p = __expf(sc[kk] - mx);
    sc[kk] = p;
    lsum += p;
  }
#pragma unroll
  for (int off = 1; off < 64; off <<= 1) lsum += __shfl_xor(lsum, off);
  if ((tid & 63) == 0) red[4 + (tid >> 6)] = lsum;
  __syncthreads();
  float rinv = 1.0f / (red[4] + red[5] + red[6] + red[7]);
  int d = tid & (DHEAD - 1);
  int grp = tid >> 6;
  float acc = 0.f;
  for (int kk = grp; kk < nk; kk += 4)
    acc += sc[kk] * v[base + (size_t)kk * DMODEL + d];
  part[grp][d] = acc;
  __syncthreads();
  if (grp == 0)
    out[base + (size_t)qi * DMODEL + d] =
        f2bf((part[0][d] + part[1][d] + part[2][d] + part[3][d]) * rinv);
}

// ------------------------------------------------------- bf16 MFMA NT GEMM
// C[m,n] = sum_k A[m,k]*B[n,k]. A: M x K bf16 row-major, B: Npad x K bf16.
// M % 128 == 0, Npad % 128 == 0, K % 32 == 0. Stores guarded to n < Nreal.
template <bool QKV, bool BIAS, bool GELU, bool RES, bool OUTBF>
__global__ __launch_bounds__(256) void gemm_bf16_nt(
    const ushort* __restrict__ A, const ushort* __restrict__ B,
    const float* __restrict__ bias, const int* __restrict__ tmask,
    const float* __restrict__ res, float* __restrict__ Cf,
    ushort* __restrict__ Cb, float* __restrict__ qb, float* __restrict__ kb,
    float* __restrict__ vb, int M, int K, int Nreal) {
  __shared__ __align__(16) ushort As[128 * 32];
  __shared__ __align__(16) ushort Bs[128 * 32];
  const int m0 = blockIdx.y * 128, n0 = blockIdx.x * 128;
  const int tid = threadIdx.x;
  const int w = tid >> 6, l = tid & 63;
  const int wr = w >> 1, wc = w & 1;
  const int fr = l & 15, ks = l >> 4;

  // staging addresses (source pre-swizzled; LDS dest linear)
  const int seg0 = w * 2, seg1 = w * 2 + 1;
  const int srow0 = seg0 * 16 + (l >> 2);
  const int srow1 = seg1 * 16 + (l >> 2);
  const int koff0 = (((l & 3) ^ ((srow0 >> 1) & 3))) * 8;
  const int koff1 = (((l & 3) ^ ((srow1 >> 1) & 3))) * 8;
  const ushort* A0 = A + (size_t)(m0 + srow0) * K + koff0;
  const ushort* A1 = A + (size_t)(m0 + srow1) * K + koff1;
  const ushort* B0 = B + (size_t)(n0 + srow0) * K + koff0;
  const ushort* B1 = B + (size_t)(n0 + srow1) * K + koff1;
  ushort* Ad0 = As + seg0 * 512;
  ushort* Ad1 = As + seg1 * 512;
  ushort* Bd0 = Bs + seg0 * 512;
  ushort* Bd1 = Bs + seg1 * 512;

  // fragment LDS offsets (swizzled read side)
  int aoff[4], boff[4];
#pragma unroll
  for (int i = 0; i < 4; ++i) {
    int ra = wr * 64 + i * 16 + fr;
    aoff[i] = ra * 32 + ((ks ^ ((ra >> 1) & 3)) * 8);
    int rb = wc * 64 + i * 16 + fr;
    boff[i] = rb * 32 + ((ks ^ ((rb >> 1) & 3)) * 8);
  }

  f32x4 acc[4][4] = {};
  for (int k0 = 0; k0 < K; k0 += 32) {
    gl_lds16(A0 + k0, Ad0);
    gl_lds16(A1 + k0, Ad1);
    gl_lds16(B0 + k0, Bd0);
    gl_lds16(B1 + k0, Bd1);
    __syncthreads();
    bf16x8 af[4], bfr[4];
#pragma unroll
    for (int i = 0; i < 4; ++i) af[i] = *reinterpret_cast<const bf16x8*>(As + aoff[i]);
#pragma unroll
    for (int i = 0; i < 4; ++i) bfr[i] = *reinterpret_cast<const bf16x8*>(Bs + boff[i]);
#pragma unroll
    for (int mi = 0; mi < 4; ++mi)
#pragma unroll
      for (int nj = 0; nj < 4; ++nj)
        acc[mi][nj] = __builtin_amdgcn_mfma_f32_16x16x32_bf16(
            af[mi], bfr[nj], acc[mi][nj], 0, 0, 0);
    __syncthreads();
  }

  // epilogue: row = ks*4 + r, col = fr
#pragma unroll
  for (int mi = 0; mi < 4; ++mi) {
#pragma unroll
    for (int nj = 0; nj < 4; ++nj) {
      int n = n0 + wc * 64 + nj * 16 + fr;
      if (n < Nreal) {
#pragma unroll
        for (int r = 0; r < 4; ++r) {
          int m = m0 + wr * 64 + mi * 16 + ks * 4 + r;
          float v = acc[mi][nj][r];
          if (QKV) {
            if (n < DMODEL) {
              v *= (1.0f - 0.5f * (float)tmask[n]) * 0.125f;
              qb[(size_t)m * DMODEL + n] = v;
            } else if (n < 2 * DMODEL) {
              kb[(size_t)m * DMODEL + (n - DMODEL)] = v;
            } else {
              vb[(size_t)m * DMODEL + (n - 2 * DMODEL)] = v;
            }
          } else {
            if (BIAS) v += bias[n];
            if (GELU) v = 0.5f * v * (1.0f + erff(v * 0.70710678118f));
            if (RES) v += res[(size_t)m * Nreal + n];
            if (OUTBF)
              Cb[(size_t)m * Nreal + n] = f2bf(v);
            else
              Cf[(size_t)m * Nreal + n] = v;
          }
        }
      }
    }
  }
}

// ---------------------------------------------------------------- launch
extern "C" void kernel_launch(void* const* d_in, const int* in_sizes, int n_in,
                              void* d_out, int out_size, void* d_ws,
                              size_t ws_size, hipStream_t stream) {
  const int* tokens = (const int*)d_in[0];
  const int* tmask = (const int*)d_in[1];
  const float* embed = (const float*)d_in[2];
  const float* pos = (const float*)d_in[3];
  const float* wq = (const float*)d_in[4];
  const float* wk = (const float*)d_in[5];
  const float* wv = (const float*)d_in[6];
  const float* wo = (const float*)d_in[7];
  const float* ln1g = (const float*)d_in[8];
  const float* ln1b = (const float*)d_in[9];
  const float* ln2g = (const float*)d_in[10];
  const float* ln2b = (const float*)d_in[11];
  const float* fw1 = (const float*)d_in[12];
  const float* fb1 = (const float*)d_in[13];
  const float* fw2 = (const float*)d_in[14];
  const float* fb2 = (const float*)d_in[15];
  const float* lnfg = (const float*)d_in[16];
  const float* lnfb = (const float*)d_in[17];

  char* wp = (char*)d_ws;
  auto alloc = [&](size_t bytes) {
    void* p = wp;
    wp += (bytes + 255) & ~(size_t)255;
    return p;
  };
  float* h = (float*)alloc((size_t)BT * DMODEL * 4);
  float* qb = (float*)alloc((size_t)BT * DMODEL * 4);
  float* kb = (float*)alloc((size_t)BT * DMODEL * 4);
  float* vb = (float*)alloc((size_t)BT * DMODEL * 4);
  ushort* xn = (ushort*)alloc((size_t)BT * DMODEL * 2);
  ushort* ab = (ushort*)alloc((size_t)BT * DMODEL * 2);
  ushort* ffb = (ushort*)alloc((size_t)BT * DFFN * 2);
  ushort* wqkv_b = (ushort*)alloc((size_t)NLAYER * 3 * DMODEL * DMODEL * 2);
  ushort* wo_b = (ushort*)alloc((size_t)NLAYER * DMODEL * DMODEL * 2);
  ushort* fw1_b = (ushort*)alloc((size_t)NLAYER * DFFN * DMODEL * 2);
  ushort* fw2_b = (ushort*)alloc((size_t)NLAYER * DMODEL * DFFN * 2);
  ushort* emb_b = (ushort*)alloc((size_t)VPAD * DMODEL * 2);

  // weight conversions
  const int per4 = DMODEL * DMODEL / 4;
  conv_qkv_kernel<<<(NLAYER * per4 + 255) / 256, 256, 0, stream>>>(wq, wqkv_b, 0);
  conv_qkv_kernel<<<(NLAYER * per4 + 255) / 256, 256, 0, stream>>>(wk, wqkv_b, per4);
  conv_qkv_kernel<<<(NLAYER * per4 + 255) / 256, 256, 0, stream>>>(wv, wqkv_b, 2 * per4);
  conv4_kernel<<<(NLAYER * per4 + 255) / 256, 256, 0, stream>>>(wo, wo_b, NLAYER * per4);
  const int nff4 = NLAYER * DFFN * DMODEL / 4;
  conv4_kernel<<<(nff4 + 255) / 256, 256, 0, stream>>>(fw1, fw1_b, nff4);
  conv4_kernel<<<(nff4 + 255) / 256, 256, 0, stream>>>(fw2, fw2_b, nff4);
  conv_embed_kernel<<<(VPAD * DMODEL / 4 + 255) / 256, 256, 0, stream>>>(embed, emb_b);

  embed_kernel<<<BT, 256, 0, stream>>>(tokens, embed, pos, h);

  const dim3 gqkv(3 * DMODEL / 128, BT / 128);
  const dim3 g768(DMODEL / 128, BT / 128);
  const dim3 gff(DFFN / 128, BT / 128);
  const dim3 gv(VPAD / 128, BT / 128);

  for (int i = 0; i < NLAYER; ++i) {
    ln_kernel<<<BT, 256, 0, stream>>>(h, ln1g + i * DMODEL, ln1b + i * DMODEL, xn);

    gemm_bf16_nt<true, false, false, false, false><<<gqkv, 256, 0, stream>>>(
        xn, wqkv_b + (size_t)i * 3 * DMODEL * DMODEL, nullptr,
        tmask + i * DMODEL, nullptr, nullptr, nullptr, qb, kb, vb,
        BT, DMODEL, 3 * DMODEL);

    attn_kernel<<<dim3(SEQ, NHEAD, BATCH), 256, 0, stream>>>(qb, kb, vb, ab);

    gemm_bf16_nt<false, false, false, true, false><<<g768, 256, 0, stream>>>(
        ab, wo_b + (size_t)i * DMODEL * DMODEL, nullptr, nullptr, h, h,
        nullptr, nullptr, nullptr, nullptr, BT, DMODEL, DMODEL);

    ln_kernel<<<BT, 256, 0, stream>>>(h, ln2g + i * DMODEL, ln2b + i * DMODEL, xn);

    gemm_bf16_nt<false, true, true, false, true><<<gff, 256, 0, stream>>>(
        xn, fw1_b + (size_t)i * DFFN * DMODEL, fb1 + i * DFFN, nullptr,
        nullptr, nullptr, ffb, nullptr, nullptr, nullptr, BT, DMODEL, DFFN);

    gemm_bf16_nt<false, true, false, true, false><<<g768, 256, 0, stream>>>(
        ffb, fw2_b + (size_t)i * DMODEL * DFFN, fb2 + i * DMODEL, nullptr, h,
        h, nullptr, nullptr, nullptr, nullptr, BT, DFFN, DMODEL);
  }

  ln_kernel<<<BT, 256, 0, stream>>>(h, lnfg, lnfb, xn);
  gemm_bf16_nt<false, false, false, false, false><<<gv, 256, 0, stream>>>(
      xn, emb_b, nullptr, nullptr, nullptr, (float*)d_out, nullptr, nullptr,
      nullptr, nullptr, BT, DMODEL, VOCABSZ);
}

// Round 3
// 1377.971 us; speedup vs baseline: 5.3821x; 2.6943x over previous
//
#include <hip/hip_runtime.h>
#include <math.h>

#define VOCABSZ 50257
#define VPAD 50304
#define DMODEL 768
#define NHEAD 12
#define NLAYER 4
#define SEQ 1024
#define BATCH 2
#define DHEAD 64
#define DFFN 3072
#define BT (BATCH * SEQ)
#define NBH (BATCH * NHEAD)

typedef __attribute__((ext_vector_type(8))) short bf16x8;
typedef __attribute__((ext_vector_type(4))) float f32x4;

__device__ __forceinline__ ushort f2bf(float f) {
  uint u = __builtin_bit_cast(uint, f);
  u = (u + 0x7fffu + ((u >> 16) & 1u)) >> 16;
  return (ushort)u;
}

__device__ __forceinline__ void gl_lds16(const ushort* g, ushort* l) {
  __builtin_amdgcn_global_load_lds(
      (const __attribute__((address_space(1))) void*)g,
      (__attribute__((address_space(3))) void*)l, 16, 0, 0);
}

// ------------------------------------------------------------- conversions
__global__ __launch_bounds__(256) void conv4_kernel(
    const float* __restrict__ src, ushort* __restrict__ dst, int n4) {
  int i = blockIdx.x * 256 + threadIdx.x;
  if (i >= n4) return;
  float4 v = reinterpret_cast<const float4*>(src)[i];
  reinterpret_cast<ushort4*>(dst)[i] =
      make_ushort4(f2bf(v.x), f2bf(v.y), f2bf(v.z), f2bf(v.w));
}

__global__ __launch_bounds__(256) void conv_qkv_kernel(
    const float* __restrict__ src, ushort* __restrict__ dst, int qoff4) {
  const int per4 = DMODEL * DMODEL / 4;
  int i = blockIdx.x * 256 + threadIdx.x;
  if (i >= NLAYER * per4) return;
  int layer = i / per4, rem = i % per4;
  float4 v = reinterpret_cast<const float4*>(src)[i];
  reinterpret_cast<ushort4*>(dst)[(size_t)layer * (3 * per4) + qoff4 + rem] =
      make_ushort4(f2bf(v.x), f2bf(v.y), f2bf(v.z), f2bf(v.w));
}

__global__ __launch_bounds__(256) void conv_embed_kernel(
    const float* __restrict__ emb, ushort* __restrict__ dst) {
  int i = blockIdx.x * 256 + threadIdx.x;
  if (i >= VPAD * DMODEL / 4) return;
  int row = (i * 4) / DMODEL;
  ushort4 o = make_ushort4(0, 0, 0, 0);
  if (row < VOCABSZ) {
    float4 v = reinterpret_cast<const float4*>(emb)[i];
    o = make_ushort4(f2bf(v.x), f2bf(v.y), f2bf(v.z), f2bf(v.w));
  }
  reinterpret_cast<ushort4*>(dst)[i] = o;
}

// ---------------------------------------------------------------- embedding
__global__ __launch_bounds__(256) void embed_kernel(
    const int* __restrict__ tok, const float* __restrict__ emb,
    const float* __restrict__ pos, float* __restrict__ h) {
  int row = blockIdx.x;
  int l = row % SEQ;
  int t = tok[row];
  int tid = threadIdx.x;
#pragma unroll
  for (int j = 0; j < 3; ++j) {
    int c = tid + j * 256;
    h[(size_t)row * DMODEL + c] =
        emb[(size_t)t * DMODEL + c] + pos[(size_t)l * DMODEL + c];
  }
}

// ---------------------------------------------------------------- layernorm
__global__ __launch_bounds__(256) void ln_kernel(
    const float* __restrict__ x, const float* __restrict__ g,
    const float* __restrict__ bta, ushort* __restrict__ o) {
  __shared__ float red[8];
  int row = blockIdx.x;
  int tid = threadIdx.x;
  const float* xr = x + (size_t)row * DMODEL;
  float v0 = xr[tid], v1 = xr[tid + 256], v2 = xr[tid + 512];
  float s = v0 + v1 + v2;
  float sq = v0 * v0 + v1 * v1 + v2 * v2;
#pragma unroll
  for (int off = 1; off < 64; off <<= 1) {
    s += __shfl_xor(s, off);
    sq += __shfl_xor(sq, off);
  }
  int wid = tid >> 6;
  if ((tid & 63) == 0) { red[wid * 2] = s; red[wid * 2 + 1] = sq; }
  __syncthreads();
  float S = red[0] + red[2] + red[4] + red[6];
  float SQ = red[1] + red[3] + red[5] + red[7];
  float mu = S * (1.0f / DMODEL);
  float var = SQ * (1.0f / DMODEL) - mu * mu;
  float r = rsqrtf(var + 1e-5f);
  ushort* orow = o + (size_t)row * DMODEL;
#pragma unroll
  for (int j = 0; j < 3; ++j) {
    int c = tid + j * 256;
    float v = (j == 0) ? v0 : (j == 1) ? v1 : v2;
    orow[c] = f2bf((v - mu) * r * g[c] + bta[c]);
  }
}

// --------------------------------------------------- V transpose (per head)
// vt[z][d][key] = v[b, key, h*64+d];  vt padded to 128 d-rows per head.
__global__ __launch_bounds__(256) void vtrans_kernel(
    const ushort* __restrict__ v, ushort* __restrict__ vt) {
  __shared__ ushort t[64][65];
  int z = blockIdx.y, b = z / NHEAD, hh = z % NHEAD;
  int key0 = blockIdx.x * 64;
  int tid = threadIdx.x;
#pragma unroll
  for (int p = 0; p < 16; ++p) {
    int idx = tid + p * 256;
    int kk = idx >> 6, d = idx & 63;
    t[kk][d] = v[((size_t)(b * SEQ + key0 + kk)) * DMODEL + hh * DHEAD + d];
  }
  __syncthreads();
#pragma unroll
  for (int p = 0; p < 16; ++p) {
    int idx = tid + p * 256;
    int d = idx >> 6, kk = idx & 63;
    vt[((size_t)(z * 128 + d)) * SEQ + key0 + kk] = t[kk][d];
  }
}

// ----------------------------------------------------- causal row softmax
// one wave per row; S fp32 [NBH*SEQ][SEQ] -> P bf16 (zeros beyond causal)
__global__ __launch_bounds__(256) void softmax_kernel(
    const float* __restrict__ S, ushort* __restrict__ P) {
  int g = blockIdx.x * 4 + (threadIdx.x >> 6);
  int lane = threadIdx.x & 63;
  int q = g & (SEQ - 1);
  size_t ro = (size_t)g * SEQ;
  float v[16];
  float mx = -1e30f;
#pragma unroll
  for (int j = 0; j < 16; ++j) {
    int col = lane + j * 64;
    v[j] = (col <= q) ? S[ro + col] : -1e30f;
    mx = fmaxf(mx, v[j]);
  }
#pragma unroll
  for (int off = 1; off < 64; off <<= 1) mx = fmaxf(mx, __shfl_xor(mx, off));
  float sum = 0.f;
#pragma unroll
  for (int j = 0; j < 16; ++j) {
    float p = __expf(v[j] - mx);
    v[j] = p;
    sum += p;
  }
#pragma unroll
  for (int off = 1; off < 64; off <<= 1) sum += __shfl_xor(sum, off);
  float rinv = 1.0f / sum;
#pragma unroll
  for (int j = 0; j < 16; ++j) {
    int col = lane + j * 64;
    P[ro + col] = f2bf(v[j] * rinv);
  }
}

// ------------------------------------------------------- bf16 MFMA NT GEMM
// C[m,n] = sum_k A[m,k]*B[n,k], strided/batched over blockIdx.z.
template <bool QKV, bool BIAS, bool GELU, bool RES, bool OUTBF, bool CTRIM,
          bool CSKIP>
__global__ __launch_bounds__(256) void gemm_bf16_nt(
    const ushort* __restrict__ A, int lda, const ushort* __restrict__ B,
    int ldb, const float* __restrict__ bias, const int* __restrict__ tmask,
    const float* __restrict__ res, float* __restrict__ Cf,
    ushort* __restrict__ Cb, int ldc, ushort* __restrict__ qb,
    ushort* __restrict__ kb, ushort* __restrict__ vb, int M, int K, int Nreal,
    int zdiv, long long sAb, long long sAh, long long sBb, long long sBh,
    long long sCb, long long sCh) {
  const int m0 = blockIdx.y * 128, n0 = blockIdx.x * 128;
  if (CSKIP && n0 >= m0 + 128) return;
  __shared__ __align__(16) ushort As[128 * 32];
  __shared__ __align__(16) ushort Bs[128 * 32];
  {
    int z = blockIdx.z, zb = z / zdiv, zh = z % zdiv;
    A += (size_t)zb * sAb + (size_t)zh * sAh;
    B += (size_t)zb * sBb + (size_t)zh * sBh;
    res += (size_t)zb * sCb + (size_t)zh * sCh;
    Cf += (size_t)zb * sCb + (size_t)zh * sCh;
    Cb += (size_t)zb * sCb + (size_t)zh * sCh;
  }
  const int tid = threadIdx.x;
  const int w = tid >> 6, l = tid & 63;
  const int wr = w >> 1, wc = w & 1;
  const int fr = l & 15, ks = l >> 4;

  const int seg0 = w * 2, seg1 = w * 2 + 1;
  const int srow0 = seg0 * 16 + (l >> 2);
  const int srow1 = seg1 * 16 + (l >> 2);
  const int koff0 = (((l & 3) ^ ((srow0 >> 1) & 3))) * 8;
  const int koff1 = (((l & 3) ^ ((srow1 >> 1) & 3))) * 8;
  const ushort* A0 = A + (size_t)(m0 + srow0) * lda + koff0;
  const ushort* A1 = A + (size_t)(m0 + srow1) * lda + koff1;
  const ushort* B0 = B + (size_t)(n0 + srow0) * ldb + koff0;
  const ushort* B1 = B + (size_t)(n0 + srow1) * ldb + koff1;
  ushort* Ad0 = As + seg0 * 512;
  ushort* Ad1 = As + seg1 * 512;
  ushort* Bd0 = Bs + seg0 * 512;
  ushort* Bd1 = Bs + seg1 * 512;

  int aoff[4], boff[4];
#pragma unroll
  for (int i = 0; i < 4; ++i) {
    int ra = wr * 64 + i * 16 + fr;
    aoff[i] = ra * 32 + ((ks ^ ((ra >> 1) & 3)) * 8);
    int rb = wc * 64 + i * 16 + fr;
    boff[i] = rb * 32 + ((ks ^ ((rb >> 1) & 3)) * 8);
  }

  const int kend = CTRIM ? (((m0 + 128) < K) ? (m0 + 128) : K) : K;
  f32x4 acc[4][4] = {};
  for (int k0 = 0; k0 < kend; k0 += 32) {
    gl_lds16(A0 + k0, Ad0);
    gl_lds16(A1 + k0, Ad1);
    gl_lds16(B0 + k0, Bd0);
    gl_lds16(B1 + k0, Bd1);
    __syncthreads();
    bf16x8 af[4], bfr[4];
#pragma unroll
    for (int i = 0; i < 4; ++i)
      af[i] = *reinterpret_cast<const bf16x8*>(As + aoff[i]);
#pragma unroll
    for (int i = 0; i < 4; ++i)
      bfr[i] = *reinterpret_cast<const bf16x8*>(Bs + boff[i]);
#pragma unroll
    for (int mi = 0; mi < 4; ++mi)
#pragma unroll
      for (int nj = 0; nj < 4; ++nj)
        acc[mi][nj] = __builtin_amdgcn_mfma_f32_16x16x32_bf16(
            af[mi], bfr[nj], acc[mi][nj], 0, 0, 0);
    __syncthreads();
  }

#pragma unroll
  for (int mi = 0; mi < 4; ++mi) {
#pragma unroll
    for (int nj = 0; nj < 4; ++nj) {
      int n = n0 + wc * 64 + nj * 16 + fr;
      if (n < Nreal) {
#pragma unroll
        for (int r = 0; r < 4; ++r) {
          int m = m0 + wr * 64 + mi * 16 + ks * 4 + r;
          float v = acc[mi][nj][r];
          if (QKV) {
            if (n < DMODEL) {
              v *= (1.0f - 0.5f * (float)tmask[n]) * 0.125f;
              qb[(size_t)m * DMODEL + n] = f2bf(v);
            } else if (n < 2 * DMODEL) {
              kb[(size_t)m * DMODEL + (n - DMODEL)] = f2bf(v);
            } else {
              vb[(size_t)m * DMODEL + (n - 2 * DMODEL)] = f2bf(v);
            }
          } else {
            if (BIAS) v += bias[n];
            if (GELU) v = 0.5f * v * (1.0f + erff(v * 0.70710678118f));
            if (RES) v += res[(size_t)m * ldc + n];
            if (OUTBF)
              Cb[(size_t)m * ldc + n] = f2bf(v);
            else
              Cf[(size_t)m * ldc + n] = v;
          }
        }
      }
    }
  }
}

// ---------------------------------------------------------------- launch
extern "C" void kernel_launch(void* const* d_in, const int* in_sizes, int n_in,
                              void* d_out, int out_size, void* d_ws,
                              size_t ws_size, hipStream_t stream) {
  const int* tokens = (const int*)d_in[0];
  const int* tmask = (const int*)d_in[1];
  const float* embed = (const float*)d_in[2];
  const float* pos = (const float*)d_in[3];
  const float* wq = (const float*)d_in[4];
  const float* wk = (const float*)d_in[5];
  const float* wv = (const float*)d_in[6];
  const float* wo = (const float*)d_in[7];
  const float* ln1g = (const float*)d_in[8];
  const float* ln1b = (const float*)d_in[9];
  const float* ln2g = (const float*)d_in[10];
  const float* ln2b = (const float*)d_in[11];
  const float* fw1 = (const float*)d_in[12];
  const float* fb1 = (const float*)d_in[13];
  const float* fw2 = (const float*)d_in[14];
  const float* fb2 = (const float*)d_in[15];
  const float* lnfg = (const float*)d_in[16];
  const float* lnfb = (const float*)d_in[17];

  char* wp = (char*)d_ws;
  auto alloc = [&](size_t bytes) {
    void* p = wp;
    wp += (bytes + 255) & ~(size_t)255;
    return p;
  };
  float* h = (float*)alloc((size_t)BT * DMODEL * 4);
  ushort* qb = (ushort*)alloc((size_t)BT * DMODEL * 2);
  ushort* kb = (ushort*)alloc((size_t)BT * DMODEL * 2);
  ushort* vb = (ushort*)alloc((size_t)BT * DMODEL * 2);
  ushort* vt = (ushort*)alloc((size_t)NBH * 128 * SEQ * 2);
  ushort* xn = (ushort*)alloc((size_t)BT * DMODEL * 2);
  ushort* ab = (ushort*)alloc((size_t)BT * DMODEL * 2);
  ushort* ffb = (ushort*)alloc((size_t)BT * DFFN * 2);
  ushort* wqkv_b = (ushort*)alloc((size_t)NLAYER * 3 * DMODEL * DMODEL * 2);
  ushort* wo_b = (ushort*)alloc((size_t)NLAYER * DMODEL * DMODEL * 2);
  ushort* fw1_b = (ushort*)alloc((size_t)NLAYER * DFFN * DMODEL * 2);
  ushort* fw2_b = (ushort*)alloc((size_t)NLAYER * DMODEL * DFFN * 2);
  ushort* emb_b = (ushort*)alloc((size_t)VPAD * DMODEL * 2);

  // S (fp32) and P (bf16) live in d_out (overwritten by logits at the end)
  float* S = (float*)d_out;
  ushort* P = (ushort*)((char*)d_out + (size_t)NBH * SEQ * SEQ * 4);

  const int per4 = DMODEL * DMODEL / 4;
  conv_qkv_kernel<<<(NLAYER * per4 + 255) / 256, 256, 0, stream>>>(wq, wqkv_b, 0);
  conv_qkv_kernel<<<(NLAYER * per4 + 255) / 256, 256, 0, stream>>>(wk, wqkv_b, per4);
  conv_qkv_kernel<<<(NLAYER * per4 + 255) / 256, 256, 0, stream>>>(wv, wqkv_b, 2 * per4);
  conv4_kernel<<<(NLAYER * per4 + 255) / 256, 256, 0, stream>>>(wo, wo_b, NLAYER * per4);
  const int nff4 = NLAYER * DFFN * DMODEL / 4;
  conv4_kernel<<<(nff4 + 255) / 256, 256, 0, stream>>>(fw1, fw1_b, nff4);
  conv4_kernel<<<(nff4 + 255) / 256, 256, 0, stream>>>(fw2, fw2_b, nff4);
  conv_embed_kernel<<<(VPAD * DMODEL / 4 + 255) / 256, 256, 0, stream>>>(embed, emb_b);

  embed_kernel<<<BT, 256, 0, stream>>>(tokens, embed, pos, h);

  const dim3 gqkv(3 * DMODEL / 128, BT / 128);
  const dim3 g768(DMODEL / 128, BT / 128);
  const dim3 gff(DFFN / 128, BT / 128);
  const dim3 gv(VPAD / 128, BT / 128);
  const dim3 gqk(SEQ / 128, SEQ / 128, NBH);
  const dim3 gpv(1, SEQ / 128, NBH);

  const long long LL = (long long)SEQ * SEQ;

  for (int i = 0; i < NLAYER; ++i) {
    ln_kernel<<<BT, 256, 0, stream>>>(h, ln1g + i * DMODEL, ln1b + i * DMODEL, xn);

    gemm_bf16_nt<true, false, false, false, false, false, false>
        <<<gqkv, 256, 0, stream>>>(
            xn, DMODEL, wqkv_b + (size_t)i * 3 * DMODEL * DMODEL, DMODEL,
            nullptr, tmask + i * DMODEL, nullptr, nullptr, nullptr, 0, qb, kb,
            vb, BT, DMODEL, 3 * DMODEL, 1, 0, 0, 0, 0, 0, 0);

    vtrans_kernel<<<dim3(SEQ / 64, NBH), 256, 0, stream>>>(vb, vt);

    // S = Q K^T (batched over (b,h)), fp32 out, causal block skip
    gemm_bf16_nt<false, false, false, false, false, false, true>
        <<<gqk, 256, 0, stream>>>(
            qb, DMODEL, kb, DMODEL, nullptr, nullptr, nullptr, S, nullptr, SEQ,
            nullptr, nullptr, nullptr, SEQ, DHEAD, SEQ, NHEAD,
            (long long)SEQ * DMODEL, DHEAD, (long long)SEQ * DMODEL, DHEAD,
            (long long)NHEAD * LL, LL);

    softmax_kernel<<<NBH * SEQ / 4, 256, 0, stream>>>(S, P);

    // O = P Vt^T (batched), bf16 out into ab, causal K trim
    gemm_bf16_nt<false, false, false, false, true, true, false>
        <<<gpv, 256, 0, stream>>>(
            P, SEQ, vt, SEQ, nullptr, nullptr, nullptr, nullptr, ab, DMODEL,
            nullptr, nullptr, nullptr, SEQ, SEQ, DHEAD, NHEAD,
            (long long)NHEAD * LL, LL, (long long)NHEAD * 128 * SEQ,
            (long long)128 * SEQ, (long long)SEQ * DMODEL, DHEAD);

    gemm_bf16_nt<false, false, false, true, false, false, false>
        <<<g768, 256, 0, stream>>>(
            ab, DMODEL, wo_b + (size_t)i * DMODEL * DMODEL, DMODEL, nullptr,
            nullptr, h, h, nullptr, DMODEL, nullptr, nullptr, nullptr, BT,
            DMODEL, DMODEL, 1, 0, 0, 0, 0, 0, 0);

    ln_kernel<<<BT, 256, 0, stream>>>(h, ln2g + i * DMODEL, ln2b + i * DMODEL, xn);

    gemm_bf16_nt<false, true, true, false, true, false, false>
        <<<gff, 256, 0, stream>>>(
            xn, DMODEL, fw1_b + (size_t)i * DFFN * DMODEL, DMODEL,
            fb1 + i * DFFN, nullptr, nullptr, nullptr, ffb, DFFN, nullptr,
            nullptr, nullptr, BT, DMODEL, DFFN, 1, 0, 0, 0, 0, 0, 0);

    gemm_bf16_nt<false, true, false, true, false, false, false>
        <<<g768, 256, 0, stream>>>(
            ffb, DFFN, fw2_b + (size_t)i * DMODEL * DFFN, DFFN,
            fb2 + i * DMODEL, nullptr, h, h, nullptr, DMODEL, nullptr, nullptr,
            nullptr, BT, DFFN, DMODEL, 1, 0, 0, 0, 0, 0, 0);
  }

  ln_kernel<<<BT, 256, 0, stream>>>(h, lnfg, lnfb, xn);
  gemm_bf16_nt<false, false, false, false, false, false, false>
      <<<gv, 256, 0, stream>>>(
          xn, DMODEL, emb_b, DMODEL, nullptr, nullptr, nullptr, (float*)d_out,
          nullptr, VOCABSZ, nullptr, nullptr, nullptr, BT, DMODEL, VOCABSZ, 1,
          0, 0, 0, 0, 0, 0);
}

// Round 4
// 1243.239 us; speedup vs baseline: 5.9653x; 1.1084x over previous
//
#include <hip/hip_runtime.h>
#include <math.h>

#define VOCABSZ 50257
#define VPAD 50304
#define DMODEL 768
#define NHEAD 12
#define NLAYER 4
#define SEQ 1024
#define BATCH 2
#define DHEAD 64
#define DFFN 3072
#define BT (BATCH * SEQ)
#define NBH (BATCH * NHEAD)

typedef __attribute__((ext_vector_type(8))) short bf16x8;
typedef __attribute__((ext_vector_type(4))) float f32x4;

__device__ __forceinline__ ushort f2bf(float f) {
  uint u = __builtin_bit_cast(uint, f);
  u = (u + 0x7fffu + ((u >> 16) & 1u)) >> 16;
  return (ushort)u;
}

__device__ __forceinline__ void gl_lds16(const ushort* g, ushort* l) {
  __builtin_amdgcn_global_load_lds(
      (const __attribute__((address_space(1))) void*)g,
      (__attribute__((address_space(3))) void*)l, 16, 0, 0);
}

// ------------------------------------------------------------- conversions
__global__ __launch_bounds__(256) void conv4_kernel(
    const float* __restrict__ src, ushort* __restrict__ dst, int n4) {
  int i = blockIdx.x * 256 + threadIdx.x;
  if (i >= n4) return;
  float4 v = reinterpret_cast<const float4*>(src)[i];
  reinterpret_cast<ushort4*>(dst)[i] =
      make_ushort4(f2bf(v.x), f2bf(v.y), f2bf(v.z), f2bf(v.w));
}

__global__ __launch_bounds__(256) void conv_qkv_kernel(
    const float* __restrict__ src, ushort* __restrict__ dst, int qoff4) {
  const int per4 = DMODEL * DMODEL / 4;
  int i = blockIdx.x * 256 + threadIdx.x;
  if (i >= NLAYER * per4) return;
  int layer = i / per4, rem = i % per4;
  float4 v = reinterpret_cast<const float4*>(src)[i];
  reinterpret_cast<ushort4*>(dst)[(size_t)layer * (3 * per4) + qoff4 + rem] =
      make_ushort4(f2bf(v.x), f2bf(v.y), f2bf(v.z), f2bf(v.w));
}

__global__ __launch_bounds__(256) void conv_embed_kernel(
    const float* __restrict__ emb, ushort* __restrict__ dst) {
  int i = blockIdx.x * 256 + threadIdx.x;
  if (i >= VPAD * DMODEL / 4) return;
  int row = (i * 4) / DMODEL;
  ushort4 o = make_ushort4(0, 0, 0, 0);
  if (row < VOCABSZ) {
    float4 v = reinterpret_cast<const float4*>(emb)[i];
    o = make_ushort4(f2bf(v.x), f2bf(v.y), f2bf(v.z), f2bf(v.w));
  }
  reinterpret_cast<ushort4*>(dst)[i] = o;
}

// ---------------------------------------------------------------- embedding
__global__ __launch_bounds__(256) void embed_kernel(
    const int* __restrict__ tok, const float* __restrict__ emb,
    const float* __restrict__ pos, float* __restrict__ h) {
  int row = blockIdx.x;
  int l = row % SEQ;
  int t = tok[row];
  int tid = threadIdx.x;
#pragma unroll
  for (int j = 0; j < 3; ++j) {
    int c = tid + j * 256;
    h[(size_t)row * DMODEL + c] =
        emb[(size_t)t * DMODEL + c] + pos[(size_t)l * DMODEL + c];
  }
}

// ---------------------------------------------------------------- layernorm
__global__ __launch_bounds__(256) void ln_kernel(
    const float* __restrict__ x, const float* __restrict__ g,
    const float* __restrict__ bta, ushort* __restrict__ o) {
  __shared__ float red[8];
  int row = blockIdx.x;
  int tid = threadIdx.x;
  const float* xr = x + (size_t)row * DMODEL;
  float v0 = xr[tid], v1 = xr[tid + 256], v2 = xr[tid + 512];
  float s = v0 + v1 + v2;
  float sq = v0 * v0 + v1 * v1 + v2 * v2;
#pragma unroll
  for (int off = 1; off < 64; off <<= 1) {
    s += __shfl_xor(s, off);
    sq += __shfl_xor(sq, off);
  }
  int wid = tid >> 6;
  if ((tid & 63) == 0) { red[wid * 2] = s; red[wid * 2 + 1] = sq; }
  __syncthreads();
  float S = red[0] + red[2] + red[4] + red[6];
  float SQ = red[1] + red[3] + red[5] + red[7];
  float mu = S * (1.0f / DMODEL);
  float var = SQ * (1.0f / DMODEL) - mu * mu;
  float r = rsqrtf(var + 1e-5f);
  ushort* orow = o + (size_t)row * DMODEL;
#pragma unroll
  for (int j = 0; j < 3; ++j) {
    int c = tid + j * 256;
    float v = (j == 0) ? v0 : (j == 1) ? v1 : v2;
    orow[c] = f2bf((v - mu) * r * g[c] + bta[c]);
  }
}

// --------------------------------------------------- V transpose (per head)
// vt[z][d][key] = v[b, key, h*64+d]
__global__ __launch_bounds__(256) void vtrans_kernel(
    const ushort* __restrict__ v, ushort* __restrict__ vt) {
  __shared__ ushort t[64][65];
  int z = blockIdx.y, b = z / NHEAD, hh = z % NHEAD;
  int key0 = blockIdx.x * 64;
  int tid = threadIdx.x;
#pragma unroll
  for (int p = 0; p < 16; ++p) {
    int idx = tid + p * 256;
    int kk = idx >> 6, d = idx & 63;
    t[kk][d] = v[((size_t)(b * SEQ + key0 + kk)) * DMODEL + hh * DHEAD + d];
  }
  __syncthreads();
#pragma unroll
  for (int p = 0; p < 16; ++p) {
    int idx = tid + p * 256;
    int d = idx >> 6, kk = idx & 63;
    vt[((size_t)(z * 64 + d)) * SEQ + key0 + kk] = t[kk][d];
  }
}

// -------------------------------------------------------- flash attention
// grid (SEQ/64, NBH), 4 waves. Each wave: 16 q-rows. K-tiles of 64.
__global__ __launch_bounds__(256) void fattn_kernel(
    const ushort* __restrict__ q, const ushort* __restrict__ k,
    const ushort* __restrict__ vt, ushort* __restrict__ o) {
  __shared__ __align__(16) ushort Ks[64 * 64];
  __shared__ __align__(16) ushort Vs[64 * 64];
  __shared__ __align__(16) ushort Ps[4][16][80];
  const int z = blockIdx.y, b = z / NHEAD, hh = z % NHEAD;
  const int q0 = (gridDim.x - 1 - blockIdx.x) * 64;  // long blocks first
  const int tid = threadIdx.x, w = tid >> 6, l = tid & 63;
  const int fr = l & 15, ks = l >> 4;
  const int qrow = q0 + w * 16 + fr;
  const ushort* qp = q + (size_t)(b * SEQ + qrow) * DMODEL + hh * DHEAD;
  const bf16x8 qf0 = *reinterpret_cast<const bf16x8*>(qp + ks * 8);
  const bf16x8 qf1 = *reinterpret_cast<const bf16x8*>(qp + 32 + ks * 8);

  const int srow = w * 16 + (l >> 3);
  const int sslot = l & 7;

  f32x4 acc_o[4] = {};
  float mrun = -1e30f, lrun = 0.f;

  for (int k0 = 0; k0 <= q0; k0 += 64) {
    // stage K [64 keys][64 dh] and Vt [64 d][64 keys], swizzled source
#pragma unroll
    for (int c = 0; c < 2; ++c) {
      int r = srow + c * 8;
      int g = sslot ^ (r & 7);
      gl_lds16(k + (size_t)(b * SEQ + k0 + r) * DMODEL + hh * DHEAD + g * 8,
               Ks + (w * 16 + c * 8) * 64);
      gl_lds16(vt + (size_t)(z * 64 + r) * SEQ + k0 + g * 8,
               Vs + (w * 16 + c * 8) * 64);
    }
    __syncthreads();
    // S^T[k][q] tile: lane holds q=fr, k = kb*16 + ks*4 + r
    f32x4 acc_s[4] = {};
#pragma unroll
    for (int kstep = 0; kstep < 2; ++kstep) {
      const bf16x8 qf = kstep ? qf1 : qf0;
#pragma unroll
      for (int kb = 0; kb < 4; ++kb) {
        int ra = kb * 16 + fr;
        bf16x8 af = *reinterpret_cast<const bf16x8*>(
            Ks + ra * 64 + (((kstep * 4 + ks) ^ (ra & 7)) * 8));
        acc_s[kb] =
            __builtin_amdgcn_mfma_f32_16x16x32_bf16(af, qf, acc_s[kb], 0, 0, 0);
      }
    }
    // online softmax
    const bool diag = (k0 == q0);
    float pm = -1e30f;
    float sv[4][4];
#pragma unroll
    for (int kb = 0; kb < 4; ++kb)
#pragma unroll
      for (int r = 0; r < 4; ++r) {
        float s = acc_s[kb][r];
        if (diag && (k0 + kb * 16 + ks * 4 + r > qrow)) s = -1e30f;
        sv[kb][r] = s;
        pm = fmaxf(pm, s);
      }
    pm = fmaxf(pm, __shfl_xor(pm, 16));
    pm = fmaxf(pm, __shfl_xor(pm, 32));
    float mnew = fmaxf(mrun, pm);
    float scale = __expf(mrun - mnew);
    float psum = 0.f;
#pragma unroll
    for (int kb = 0; kb < 4; ++kb) {
      float p0 = __expf(sv[kb][0] - mnew);
      float p1 = __expf(sv[kb][1] - mnew);
      float p2 = __expf(sv[kb][2] - mnew);
      float p3 = __expf(sv[kb][3] - mnew);
      psum += (p0 + p1) + (p2 + p3);
      *reinterpret_cast<ushort4*>(&Ps[w][fr][kb * 16 + ks * 4]) =
          make_ushort4(f2bf(p0), f2bf(p1), f2bf(p2), f2bf(p3));
    }
    psum += __shfl_xor(psum, 16);
    psum += __shfl_xor(psum, 32);
    lrun = lrun * scale + psum;
    mrun = mnew;
#pragma unroll
    for (int db = 0; db < 4; ++db) acc_o[db] *= scale;
    // O^T[d][q] += Vt P^T
#pragma unroll
    for (int kstep = 0; kstep < 2; ++kstep) {
      bf16x8 pf =
          *reinterpret_cast<const bf16x8*>(&Ps[w][fr][kstep * 32 + ks * 8]);
#pragma unroll
      for (int db = 0; db < 4; ++db) {
        int rd = db * 16 + fr;
        bf16x8 vf = *reinterpret_cast<const bf16x8*>(
            Vs + rd * 64 + (((kstep * 4 + ks) ^ (rd & 7)) * 8));
        acc_o[db] =
            __builtin_amdgcn_mfma_f32_16x16x32_bf16(vf, pf, acc_o[db], 0, 0, 0);
      }
    }
    __syncthreads();
  }
  float rinv = 1.0f / lrun;
#pragma unroll
  for (int db = 0; db < 4; ++db) {
    ushort4 o4 =
        make_ushort4(f2bf(acc_o[db][0] * rinv), f2bf(acc_o[db][1] * rinv),
                     f2bf(acc_o[db][2] * rinv), f2bf(acc_o[db][3] * rinv));
    *reinterpret_cast<ushort4*>(o + (size_t)(b * SEQ + qrow) * DMODEL +
                                hh * DHEAD + db * 16 + ks * 4) = o4;
  }
}

// ------------------------------------------------------- bf16 MFMA NT GEMM
// C[m,n] = sum_k A[m,k]*B[n,k]. A: M x K bf16, B: Npad x K bf16.
template <bool QKV, bool BIAS, bool GELU, bool RES, bool OUTBF, bool SWAPXY>
__global__ __launch_bounds__(256) void gemm_bf16_nt(
    const ushort* __restrict__ A, const ushort* __restrict__ B,
    const float* __restrict__ bias, const int* __restrict__ tmask,
    const float* __restrict__ res, float* __restrict__ Cf,
    ushort* __restrict__ Cb, int ldc, ushort* __restrict__ qb,
    ushort* __restrict__ kb, ushort* __restrict__ vb, int M, int K,
    int Nreal) {
  __shared__ __align__(16) ushort As[128 * 32];
  __shared__ __align__(16) ushort Bs[128 * 32];
  const int bnx = SWAPXY ? blockIdx.y : blockIdx.x;
  const int bmy = SWAPXY ? blockIdx.x : blockIdx.y;
  const int m0 = bmy * 128, n0 = bnx * 128;
  const int tid = threadIdx.x;
  const int w = tid >> 6, l = tid & 63;
  const int wr = w >> 1, wc = w & 1;
  const int fr = l & 15, ks = l >> 4;

  const int seg0 = w * 2, seg1 = w * 2 + 1;
  const int srow0 = seg0 * 16 + (l >> 2);
  const int srow1 = seg1 * 16 + (l >> 2);
  const int koff0 = (((l & 3) ^ ((srow0 >> 1) & 3))) * 8;
  const int koff1 = (((l & 3) ^ ((srow1 >> 1) & 3))) * 8;
  const ushort* A0 = A + (size_t)(m0 + srow0) * K + koff0;
  const ushort* A1 = A + (size_t)(m0 + srow1) * K + koff1;
  const ushort* B0 = B + (size_t)(n0 + srow0) * K + koff0;
  const ushort* B1 = B + (size_t)(n0 + srow1) * K + koff1;
  ushort* Ad0 = As + seg0 * 512;
  ushort* Ad1 = As + seg1 * 512;
  ushort* Bd0 = Bs + seg0 * 512;
  ushort* Bd1 = Bs + seg1 * 512;

  int aoff[4], boff[4];
#pragma unroll
  for (int i = 0; i < 4; ++i) {
    int ra = wr * 64 + i * 16 + fr;
    aoff[i] = ra * 32 + ((ks ^ ((ra >> 1) & 3)) * 8);
    int rb = wc * 64 + i * 16 + fr;
    boff[i] = rb * 32 + ((ks ^ ((rb >> 1) & 3)) * 8);
  }

  f32x4 acc[4][4] = {};
  for (int k0 = 0; k0 < K; k0 += 32) {
    gl_lds16(A0 + k0, Ad0);
    gl_lds16(A1 + k0, Ad1);
    gl_lds16(B0 + k0, Bd0);
    gl_lds16(B1 + k0, Bd1);
    __syncthreads();
    bf16x8 af[4], bfr[4];
#pragma unroll
    for (int i = 0; i < 4; ++i)
      af[i] = *reinterpret_cast<const bf16x8*>(As + aoff[i]);
#pragma unroll
    for (int i = 0; i < 4; ++i)
      bfr[i] = *reinterpret_cast<const bf16x8*>(Bs + boff[i]);
#pragma unroll
    for (int mi = 0; mi < 4; ++mi)
#pragma unroll
      for (int nj = 0; nj < 4; ++nj)
        acc[mi][nj] = __builtin_amdgcn_mfma_f32_16x16x32_bf16(
            af[mi], bfr[nj], acc[mi][nj], 0, 0, 0);
    __syncthreads();
  }

#pragma unroll
  for (int mi = 0; mi < 4; ++mi) {
#pragma unroll
    for (int nj = 0; nj < 4; ++nj) {
      int n = n0 + wc * 64 + nj * 16 + fr;
      if (n < Nreal) {
#pragma unroll
        for (int r = 0; r < 4; ++r) {
          int m = m0 + wr * 64 + mi * 16 + ks * 4 + r;
          float v = acc[mi][nj][r];
          if (QKV) {
            if (n < DMODEL) {
              v *= (1.0f - 0.5f * (float)tmask[n]) * 0.125f;
              qb[(size_t)m * DMODEL + n] = f2bf(v);
            } else if (n < 2 * DMODEL) {
              kb[(size_t)m * DMODEL + (n - DMODEL)] = f2bf(v);
            } else {
              vb[(size_t)m * DMODEL + (n - 2 * DMODEL)] = f2bf(v);
            }
          } else {
            if (BIAS) v += bias[n];
            if (GELU) v = 0.5f * v * (1.0f + erff(v * 0.70710678118f));
            if (RES) v += res[(size_t)m * ldc + n];
            if (OUTBF)
              Cb[(size_t)m * ldc + n] = f2bf(v);
            else
              Cf[(size_t)m * ldc + n] = v;
          }
        }
      }
    }
  }
}

// ---------------------------------------------------------------- launch
extern "C" void kernel_launch(void* const* d_in, const int* in_sizes, int n_in,
                              void* d_out, int out_size, void* d_ws,
                              size_t ws_size, hipStream_t stream) {
  const int* tokens = (const int*)d_in[0];
  const int* tmask = (const int*)d_in[1];
  const float* embed = (const float*)d_in[2];
  const float* pos = (const float*)d_in[3];
  const float* wq = (const float*)d_in[4];
  const float* wk = (const float*)d_in[5];
  const float* wv = (const float*)d_in[6];
  const float* wo = (const float*)d_in[7];
  const float* ln1g = (const float*)d_in[8];
  const float* ln1b = (const float*)d_in[9];
  const float* ln2g = (const float*)d_in[10];
  const float* ln2b = (const float*)d_in[11];
  const float* fw1 = (const float*)d_in[12];
  const float* fb1 = (const float*)d_in[13];
  const float* fw2 = (const float*)d_in[14];
  const float* fb2 = (const float*)d_in[15];
  const float* lnfg = (const float*)d_in[16];
  const float* lnfb = (const float*)d_in[17];

  char* wp = (char*)d_ws;
  auto alloc = [&](size_t bytes) {
    void* p = wp;
    wp += (bytes + 255) & ~(size_t)255;
    return p;
  };
  float* h = (float*)alloc((size_t)BT * DMODEL * 4);
  ushort* qb = (ushort*)alloc((size_t)BT * DMODEL * 2);
  ushort* kb = (ushort*)alloc((size_t)BT * DMODEL * 2);
  ushort* vb = (ushort*)alloc((size_t)BT * DMODEL * 2);
  ushort* vt = (ushort*)alloc((size_t)NBH * DHEAD * SEQ * 2);
  ushort* xn = (ushort*)alloc((size_t)BT * DMODEL * 2);
  ushort* ab = (ushort*)alloc((size_t)BT * DMODEL * 2);
  ushort* ffb = (ushort*)alloc((size_t)BT * DFFN * 2);
  ushort* wqkv_b = (ushort*)alloc((size_t)NLAYER * 3 * DMODEL * DMODEL * 2);
  ushort* wo_b = (ushort*)alloc((size_t)NLAYER * DMODEL * DMODEL * 2);
  ushort* fw1_b = (ushort*)alloc((size_t)NLAYER * DFFN * DMODEL * 2);
  ushort* fw2_b = (ushort*)alloc((size_t)NLAYER * DMODEL * DFFN * 2);
  ushort* emb_b = (ushort*)alloc((size_t)VPAD * DMODEL * 2);

  const int per4 = DMODEL * DMODEL / 4;
  conv_qkv_kernel<<<(NLAYER * per4 + 255) / 256, 256, 0, stream>>>(wq, wqkv_b, 0);
  conv_qkv_kernel<<<(NLAYER * per4 + 255) / 256, 256, 0, stream>>>(wk, wqkv_b, per4);
  conv_qkv_kernel<<<(NLAYER * per4 + 255) / 256, 256, 0, stream>>>(wv, wqkv_b, 2 * per4);
  conv4_kernel<<<(NLAYER * per4 + 255) / 256, 256, 0, stream>>>(wo, wo_b, NLAYER * per4);
  const int nff4 = NLAYER * DFFN * DMODEL / 4;
  conv4_kernel<<<(nff4 + 255) / 256, 256, 0, stream>>>(fw1, fw1_b, nff4);
  conv4_kernel<<<(nff4 + 255) / 256, 256, 0, stream>>>(fw2, fw2_b, nff4);
  conv_embed_kernel<<<(VPAD * DMODEL / 4 + 255) / 256, 256, 0, stream>>>(embed, emb_b);

  embed_kernel<<<BT, 256, 0, stream>>>(tokens, embed, pos, h);

  const dim3 gqkv(3 * DMODEL / 128, BT / 128);
  const dim3 g768(DMODEL / 128, BT / 128);
  const dim3 gff(DFFN / 128, BT / 128);
  const dim3 gv(BT / 128, VPAD / 128);  // swapped: m fast for B-panel reuse

  for (int i = 0; i < NLAYER; ++i) {
    ln_kernel<<<BT, 256, 0, stream>>>(h, ln1g + i * DMODEL, ln1b + i * DMODEL, xn);

    gemm_bf16_nt<true, false, false, false, false, false>
        <<<gqkv, 256, 0, stream>>>(
            xn, wqkv_b + (size_t)i * 3 * DMODEL * DMODEL, nullptr,
            tmask + i * DMODEL, nullptr, nullptr, nullptr, 0, qb, kb, vb, BT,
            DMODEL, 3 * DMODEL);

    vtrans_kernel<<<dim3(SEQ / 64, NBH), 256, 0, stream>>>(vb, vt);

    fattn_kernel<<<dim3(SEQ / 64, NBH), 256, 0, stream>>>(qb, kb, vt, ab);

    gemm_bf16_nt<false, false, false, true, false, false>
        <<<g768, 256, 0, stream>>>(
            ab, wo_b + (size_t)i * DMODEL * DMODEL, nullptr, nullptr, h, h,
            nullptr, DMODEL, nullptr, nullptr, nullptr, BT, DMODEL, DMODEL);

    ln_kernel<<<BT, 256, 0, stream>>>(h, ln2g + i * DMODEL, ln2b + i * DMODEL, xn);

    gemm_bf16_nt<false, true, true, false, true, false>
        <<<gff, 256, 0, stream>>>(
            xn, fw1_b + (size_t)i * DFFN * DMODEL, fb1 + i * DFFN, nullptr,
            nullptr, nullptr, ffb, DFFN, nullptr, nullptr, nullptr, BT, DMODEL,
            DFFN);

    gemm_bf16_nt<false, true, false, true, false, false>
        <<<g768, 256, 0, stream>>>(
            ffb, fw2_b + (size_t)i * DMODEL * DFFN, fb2 + i * DMODEL, nullptr,
            h, h, nullptr, DMODEL, nullptr, nullptr, nullptr, BT, DFFN,
            DMODEL);
  }

  ln_kernel<<<BT, 256, 0, stream>>>(h, lnfg, lnfb, xn);
  gemm_bf16_nt<false, false, false, false, false, true>
      <<<gv, 256, 0, stream>>>(
          xn, emb_b, nullptr, nullptr, nullptr, (float*)d_out, nullptr,
          VOCABSZ, nullptr, nullptr, nullptr, BT, DMODEL, VOCABSZ);
}

// Round 5
// 1058.908 us; speedup vs baseline: 7.0038x; 1.1741x over previous
//
#include <hip/hip_runtime.h>
#include <math.h>

#define VOCABSZ 50257
#define VPAD 50304
#define DMODEL 768
#define NHEAD 12
#define NLAYER 4
#define SEQ 1024
#define BATCH 2
#define DHEAD 64
#define DFFN 3072
#define BT (BATCH * SEQ)
#define NBH (BATCH * NHEAD)

typedef __attribute__((ext_vector_type(8))) short bf16x8;
typedef __attribute__((ext_vector_type(4))) float f32x4;

__device__ __forceinline__ ushort f2bf(float f) {
  uint u = __builtin_bit_cast(uint, f);
  u = (u + 0x7fffu + ((u >> 16) & 1u)) >> 16;
  return (ushort)u;
}

__device__ __forceinline__ void gl_lds16(const ushort* g, ushort* l) {
  __builtin_amdgcn_global_load_lds(
      (const __attribute__((address_space(1))) void*)g,
      (__attribute__((address_space(3))) void*)l, 16, 0, 0);
}

// ------------------------------------------------------------- conversions
__global__ __launch_bounds__(256) void conv4_kernel(
    const float* __restrict__ src, ushort* __restrict__ dst, int n4) {
  int i = blockIdx.x * 256 + threadIdx.x;
  if (i >= n4) return;
  float4 v = reinterpret_cast<const float4*>(src)[i];
  reinterpret_cast<ushort4*>(dst)[i] =
      make_ushort4(f2bf(v.x), f2bf(v.y), f2bf(v.z), f2bf(v.w));
}

__global__ __launch_bounds__(256) void conv_qkv_kernel(
    const float* __restrict__ src, ushort* __restrict__ dst, int qoff4) {
  const int per4 = DMODEL * DMODEL / 4;
  int i = blockIdx.x * 256 + threadIdx.x;
  if (i >= NLAYER * per4) return;
  int layer = i / per4, rem = i % per4;
  float4 v = reinterpret_cast<const float4*>(src)[i];
  reinterpret_cast<ushort4*>(dst)[(size_t)layer * (3 * per4) + qoff4 + rem] =
      make_ushort4(f2bf(v.x), f2bf(v.y), f2bf(v.z), f2bf(v.w));
}

__global__ __launch_bounds__(256) void conv_embed_kernel(
    const float* __restrict__ emb, ushort* __restrict__ dst) {
  int i = blockIdx.x * 256 + threadIdx.x;
  if (i >= VPAD * DMODEL / 4) return;
  int row = (i * 4) / DMODEL;
  ushort4 o = make_ushort4(0, 0, 0, 0);
  if (row < VOCABSZ) {
    float4 v = reinterpret_cast<const float4*>(emb)[i];
    o = make_ushort4(f2bf(v.x), f2bf(v.y), f2bf(v.z), f2bf(v.w));
  }
  reinterpret_cast<ushort4*>(dst)[i] = o;
}

// ---------------------------------------------------------------- embedding
__global__ __launch_bounds__(256) void embed_kernel(
    const int* __restrict__ tok, const float* __restrict__ emb,
    const float* __restrict__ pos, float* __restrict__ h) {
  int row = blockIdx.x;
  int l = row % SEQ;
  int t = tok[row];
  int tid = threadIdx.x;
#pragma unroll
  for (int j = 0; j < 3; ++j) {
    int c = tid + j * 256;
    h[(size_t)row * DMODEL + c] =
        emb[(size_t)t * DMODEL + c] + pos[(size_t)l * DMODEL + c];
  }
}

// ---------------------------------------------------------------- layernorm
__global__ __launch_bounds__(256) void ln_kernel(
    const float* __restrict__ x, const float* __restrict__ g,
    const float* __restrict__ bta, ushort* __restrict__ o) {
  __shared__ float red[8];
  int row = blockIdx.x;
  int tid = threadIdx.x;
  const float* xr = x + (size_t)row * DMODEL;
  float v0 = xr[tid], v1 = xr[tid + 256], v2 = xr[tid + 512];
  float s = v0 + v1 + v2;
  float sq = v0 * v0 + v1 * v1 + v2 * v2;
#pragma unroll
  for (int off = 1; off < 64; off <<= 1) {
    s += __shfl_xor(s, off);
    sq += __shfl_xor(sq, off);
  }
  int wid = tid >> 6;
  if ((tid & 63) == 0) { red[wid * 2] = s; red[wid * 2 + 1] = sq; }
  __syncthreads();
  float S = red[0] + red[2] + red[4] + red[6];
  float SQ = red[1] + red[3] + red[5] + red[7];
  float mu = S * (1.0f / DMODEL);
  float var = SQ * (1.0f / DMODEL) - mu * mu;
  float r = rsqrtf(var + 1e-5f);
  ushort* orow = o + (size_t)row * DMODEL;
#pragma unroll
  for (int j = 0; j < 3; ++j) {
    int c = tid + j * 256;
    float v = (j == 0) ? v0 : (j == 1) ? v1 : v2;
    orow[c] = f2bf((v - mu) * r * g[c] + bta[c]);
  }
}

// ------------------------------------------------- split-K reduce (+res/bias)
template <int KS, bool BIAS>
__global__ __launch_bounds__(256) void redk_kernel(
    const float* __restrict__ part, const float* __restrict__ bias,
    float* __restrict__ h) {
  int row = blockIdx.x;
  int tid = threadIdx.x;
#pragma unroll
  for (int j = 0; j < 3; ++j) {
    int c = tid + j * 256;
    size_t off = (size_t)row * DMODEL + c;
    float acc = h[off];
    if (BIAS) acc += bias[c];
#pragma unroll
    for (int z = 0; z < KS; ++z)
      acc += part[(size_t)z * BT * DMODEL + off];
    h[off] = acc;
  }
}

// --------------------------------------------------- V transpose (per head)
__global__ __launch_bounds__(256) void vtrans_kernel(
    const ushort* __restrict__ v, ushort* __restrict__ vt) {
  __shared__ ushort t[64][65];
  int z = blockIdx.y, b = z / NHEAD, hh = z % NHEAD;
  int key0 = blockIdx.x * 64;
  int tid = threadIdx.x;
#pragma unroll
  for (int p = 0; p < 16; ++p) {
    int idx = tid + p * 256;
    int kk = idx >> 6, d = idx & 63;
    t[kk][d] = v[((size_t)(b * SEQ + key0 + kk)) * DMODEL + hh * DHEAD + d];
  }
  __syncthreads();
#pragma unroll
  for (int p = 0; p < 16; ++p) {
    int idx = tid + p * 256;
    int d = idx >> 6, kk = idx & 63;
    vt[((size_t)(z * 64 + d)) * SEQ + key0 + kk] = t[kk][d];
  }
}

// -------------------------------------------------------- flash attention
__global__ __launch_bounds__(256) void fattn_kernel(
    const ushort* __restrict__ q, const ushort* __restrict__ k,
    const ushort* __restrict__ vt, ushort* __restrict__ o) {
  __shared__ __align__(16) ushort Ks[64 * 64];
  __shared__ __align__(16) ushort Vs[64 * 64];
  __shared__ __align__(16) ushort Ps[4][16][80];
  const int z = blockIdx.y, b = z / NHEAD, hh = z % NHEAD;
  const int q0 = (gridDim.x - 1 - blockIdx.x) * 64;  // long blocks first
  const int tid = threadIdx.x, w = tid >> 6, l = tid & 63;
  const int fr = l & 15, ks = l >> 4;
  const int qrow = q0 + w * 16 + fr;
  const ushort* qp = q + (size_t)(b * SEQ + qrow) * DMODEL + hh * DHEAD;
  const bf16x8 qf0 = *reinterpret_cast<const bf16x8*>(qp + ks * 8);
  const bf16x8 qf1 = *reinterpret_cast<const bf16x8*>(qp + 32 + ks * 8);

  const int srow = w * 16 + (l >> 3);
  const int sslot = l & 7;

  f32x4 acc_o[4] = {};
  float mrun = -1e30f, lrun = 0.f;

  for (int k0 = 0; k0 <= q0; k0 += 64) {
#pragma unroll
    for (int c = 0; c < 2; ++c) {
      int r = srow + c * 8;
      int g = sslot ^ (r & 7);
      gl_lds16(k + (size_t)(b * SEQ + k0 + r) * DMODEL + hh * DHEAD + g * 8,
               Ks + (w * 16 + c * 8) * 64);
      gl_lds16(vt + (size_t)(z * 64 + r) * SEQ + k0 + g * 8,
               Vs + (w * 16 + c * 8) * 64);
    }
    __syncthreads();
    f32x4 acc_s[4] = {};
#pragma unroll
    for (int kstep = 0; kstep < 2; ++kstep) {
      const bf16x8 qf = kstep ? qf1 : qf0;
#pragma unroll
      for (int kb = 0; kb < 4; ++kb) {
        int ra = kb * 16 + fr;
        bf16x8 af = *reinterpret_cast<const bf16x8*>(
            Ks + ra * 64 + (((kstep * 4 + ks) ^ (ra & 7)) * 8));
        acc_s[kb] =
            __builtin_amdgcn_mfma_f32_16x16x32_bf16(af, qf, acc_s[kb], 0, 0, 0);
      }
    }
    const bool diag = (k0 == q0);
    float pm = -1e30f;
    float sv[4][4];
#pragma unroll
    for (int kb = 0; kb < 4; ++kb)
#pragma unroll
      for (int r = 0; r < 4; ++r) {
        float s = acc_s[kb][r];
        if (diag && (k0 + kb * 16 + ks * 4 + r > qrow)) s = -1e30f;
        sv[kb][r] = s;
        pm = fmaxf(pm, s);
      }
    pm = fmaxf(pm, __shfl_xor(pm, 16));
    pm = fmaxf(pm, __shfl_xor(pm, 32));
    float mnew = fmaxf(mrun, pm);
    float scale = __expf(mrun - mnew);
    float psum = 0.f;
#pragma unroll
    for (int kb = 0; kb < 4; ++kb) {
      float p0 = __expf(sv[kb][0] - mnew);
      float p1 = __expf(sv[kb][1] - mnew);
      float p2 = __expf(sv[kb][2] - mnew);
      float p3 = __expf(sv[kb][3] - mnew);
      psum += (p0 + p1) + (p2 + p3);
      *reinterpret_cast<ushort4*>(&Ps[w][fr][kb * 16 + ks * 4]) =
          make_ushort4(f2bf(p0), f2bf(p1), f2bf(p2), f2bf(p3));
    }
    psum += __shfl_xor(psum, 16);
    psum += __shfl_xor(psum, 32);
    lrun = lrun * scale + psum;
    mrun = mnew;
#pragma unroll
    for (int db = 0; db < 4; ++db) acc_o[db] *= scale;
#pragma unroll
    for (int kstep = 0; kstep < 2; ++kstep) {
      bf16x8 pf =
          *reinterpret_cast<const bf16x8*>(&Ps[w][fr][kstep * 32 + ks * 8]);
#pragma unroll
      for (int db = 0; db < 4; ++db) {
        int rd = db * 16 + fr;
        bf16x8 vf = *reinterpret_cast<const bf16x8*>(
            Vs + rd * 64 + (((kstep * 4 + ks) ^ (rd & 7)) * 8));
        acc_o[db] =
            __builtin_amdgcn_mfma_f32_16x16x32_bf16(vf, pf, acc_o[db], 0, 0, 0);
      }
    }
    __syncthreads();
  }
  float rinv = 1.0f / lrun;
#pragma unroll
  for (int db = 0; db < 4; ++db) {
    ushort4 o4 =
        make_ushort4(f2bf(acc_o[db][0] * rinv), f2bf(acc_o[db][1] * rinv),
                     f2bf(acc_o[db][2] * rinv), f2bf(acc_o[db][3] * rinv));
    *reinterpret_cast<ushort4*>(o + (size_t)(b * SEQ + qrow) * DMODEL +
                                hh * DHEAD + db * 16 + ks * 4) = o4;
  }
}

// ------------------------------------------------------- bf16 MFMA NT GEMM
// C[m,n] = sum_k A[m,k]*B[n,k]. A: M x K bf16, B: Npad x K bf16.
// SWZ: 1-D grid, XCD-chunked block swizzle (grid multiple of 8).
// PART: split-K partials; blockIdx.z selects K-chunk of size kchunk,
//       raw fp32 store at Cf + z*M*ldc.
template <bool QKV, bool BIAS, bool GELU, bool RES, bool OUTBF, bool SWZ,
          bool PART>
__global__ __launch_bounds__(256) void gemm_bf16_nt(
    const ushort* __restrict__ A, const ushort* __restrict__ B,
    const float* __restrict__ bias, const int* __restrict__ tmask,
    const float* __restrict__ res, float* __restrict__ Cf,
    ushort* __restrict__ Cb, int ldc, ushort* __restrict__ qb,
    ushort* __restrict__ kb, ushort* __restrict__ vb, int M, int K, int Nreal,
    int kchunk) {
  __shared__ __align__(16) ushort As[128 * 32];
  __shared__ __align__(16) ushort Bs[128 * 32];
  int bnx, bmy;
  if (SWZ) {
    int bid = blockIdx.x;
    int chunk = gridDim.x >> 3;
    int wgid = (bid & 7) * chunk + (bid >> 3);
    int mb = M >> 7;
    bmy = wgid % mb;
    bnx = wgid / mb;
  } else {
    bnx = blockIdx.x;
    bmy = blockIdx.y;
  }
  const int m0 = bmy * 128, n0 = bnx * 128;
  const int kbeg = PART ? blockIdx.z * kchunk : 0;
  const int kend = PART ? kbeg + kchunk : K;
  if (PART) Cf += (size_t)blockIdx.z * M * ldc;
  const int tid = threadIdx.x;
  const int w = tid >> 6, l = tid & 63;
  const int wr = w >> 1, wc = w & 1;
  const int fr = l & 15, ks = l >> 4;

  const int seg0 = w * 2, seg1 = w * 2 + 1;
  const int srow0 = seg0 * 16 + (l >> 2);
  const int srow1 = seg1 * 16 + (l >> 2);
  const int koff0 = (((l & 3) ^ ((srow0 >> 1) & 3))) * 8;
  const int koff1 = (((l & 3) ^ ((srow1 >> 1) & 3))) * 8;
  const ushort* A0 = A + (size_t)(m0 + srow0) * K + koff0;
  const ushort* A1 = A + (size_t)(m0 + srow1) * K + koff1;
  const ushort* B0 = B + (size_t)(n0 + srow0) * K + koff0;
  const ushort* B1 = B + (size_t)(n0 + srow1) * K + koff1;
  ushort* Ad0 = As + seg0 * 512;
  ushort* Ad1 = As + seg1 * 512;
  ushort* Bd0 = Bs + seg0 * 512;
  ushort* Bd1 = Bs + seg1 * 512;

  int aoff[4], boff[4];
#pragma unroll
  for (int i = 0; i < 4; ++i) {
    int ra = wr * 64 + i * 16 + fr;
    aoff[i] = ra * 32 + ((ks ^ ((ra >> 1) & 3)) * 8);
    int rb = wc * 64 + i * 16 + fr;
    boff[i] = rb * 32 + ((ks ^ ((rb >> 1) & 3)) * 8);
  }

  f32x4 acc[4][4] = {};
  for (int k0 = kbeg; k0 < kend; k0 += 32) {
    gl_lds16(A0 + k0, Ad0);
    gl_lds16(A1 + k0, Ad1);
    gl_lds16(B0 + k0, Bd0);
    gl_lds16(B1 + k0, Bd1);
    __syncthreads();
    bf16x8 af[4], bfr[4];
#pragma unroll
    for (int i = 0; i < 4; ++i)
      af[i] = *reinterpret_cast<const bf16x8*>(As + aoff[i]);
#pragma unroll
    for (int i = 0; i < 4; ++i)
      bfr[i] = *reinterpret_cast<const bf16x8*>(Bs + boff[i]);
#pragma unroll
    for (int mi = 0; mi < 4; ++mi)
#pragma unroll
      for (int nj = 0; nj < 4; ++nj)
        acc[mi][nj] = __builtin_amdgcn_mfma_f32_16x16x32_bf16(
            af[mi], bfr[nj], acc[mi][nj], 0, 0, 0);
    __syncthreads();
  }

#pragma unroll
  for (int mi = 0; mi < 4; ++mi) {
#pragma unroll
    for (int nj = 0; nj < 4; ++nj) {
      int n = n0 + wc * 64 + nj * 16 + fr;
      if (n < Nreal) {
#pragma unroll
        for (int r = 0; r < 4; ++r) {
          int m = m0 + wr * 64 + mi * 16 + ks * 4 + r;
          float v = acc[mi][nj][r];
          if (PART) {
            Cf[(size_t)m * ldc + n] = v;
          } else if (QKV) {
            if (n < DMODEL) {
              v *= (1.0f - 0.5f * (float)tmask[n]) * 0.125f;
              qb[(size_t)m * DMODEL + n] = f2bf(v);
            } else if (n < 2 * DMODEL) {
              kb[(size_t)m * DMODEL + (n - DMODEL)] = f2bf(v);
            } else {
              vb[(size_t)m * DMODEL + (n - 2 * DMODEL)] = f2bf(v);
            }
          } else {
            if (BIAS) v += bias[n];
            if (GELU) v = 0.5f * v * (1.0f + erff(v * 0.70710678118f));
            if (RES) v += res[(size_t)m * ldc + n];
            if (OUTBF)
              Cb[(size_t)m * ldc + n] = f2bf(v);
            else
              Cf[(size_t)m * ldc + n] = v;
          }
        }
      }
    }
  }
}

// ---------------------------------------------------------------- launch
extern "C" void kernel_launch(void* const* d_in, const int* in_sizes, int n_in,
                              void* d_out, int out_size, void* d_ws,
                              size_t ws_size, hipStream_t stream) {
  const int* tokens = (const int*)d_in[0];
  const int* tmask = (const int*)d_in[1];
  const float* embed = (const float*)d_in[2];
  const float* pos = (const float*)d_in[3];
  const float* wq = (const float*)d_in[4];
  const float* wk = (const float*)d_in[5];
  const float* wv = (const float*)d_in[6];
  const float* wo = (const float*)d_in[7];
  const float* ln1g = (const float*)d_in[8];
  const float* ln1b = (const float*)d_in[9];
  const float* ln2g = (const float*)d_in[10];
  const float* ln2b = (const float*)d_in[11];
  const float* fw1 = (const float*)d_in[12];
  const float* fb1 = (const float*)d_in[13];
  const float* fw2 = (const float*)d_in[14];
  const float* fb2 = (const float*)d_in[15];
  const float* lnfg = (const float*)d_in[16];
  const float* lnfb = (const float*)d_in[17];

  char* wp = (char*)d_ws;
  auto alloc = [&](size_t bytes) {
    void* p = wp;
    wp += (bytes + 255) & ~(size_t)255;
    return p;
  };
  float* h = (float*)alloc((size_t)BT * DMODEL * 4);
  float* part = (float*)alloc((size_t)4 * BT * DMODEL * 4);
  ushort* qb = (ushort*)alloc((size_t)BT * DMODEL * 2);
  ushort* kb = (ushort*)alloc((size_t)BT * DMODEL * 2);
  ushort* vb = (ushort*)alloc((size_t)BT * DMODEL * 2);
  ushort* vt = (ushort*)alloc((size_t)NBH * DHEAD * SEQ * 2);
  ushort* xn = (ushort*)alloc((size_t)BT * DMODEL * 2);
  ushort* ab = (ushort*)alloc((size_t)BT * DMODEL * 2);
  ushort* ffb = (ushort*)alloc((size_t)BT * DFFN * 2);
  ushort* wqkv_b = (ushort*)alloc((size_t)NLAYER * 3 * DMODEL * DMODEL * 2);
  ushort* wo_b = (ushort*)alloc((size_t)NLAYER * DMODEL * DMODEL * 2);
  ushort* fw1_b = (ushort*)alloc((size_t)NLAYER * DFFN * DMODEL * 2);
  ushort* fw2_b = (ushort*)alloc((size_t)NLAYER * DMODEL * DFFN * 2);
  ushort* emb_b = (ushort*)alloc((size_t)VPAD * DMODEL * 2);

  const int per4 = DMODEL * DMODEL / 4;
  conv_qkv_kernel<<<(NLAYER * per4 + 255) / 256, 256, 0, stream>>>(wq, wqkv_b, 0);
  conv_qkv_kernel<<<(NLAYER * per4 + 255) / 256, 256, 0, stream>>>(wk, wqkv_b, per4);
  conv_qkv_kernel<<<(NLAYER * per4 + 255) / 256, 256, 0, stream>>>(wv, wqkv_b, 2 * per4);
  conv4_kernel<<<(NLAYER * per4 + 255) / 256, 256, 0, stream>>>(wo, wo_b, NLAYER * per4);
  const int nff4 = NLAYER * DFFN * DMODEL / 4;
  conv4_kernel<<<(nff4 + 255) / 256, 256, 0, stream>>>(fw1, fw1_b, nff4);
  conv4_kernel<<<(nff4 + 255) / 256, 256, 0, stream>>>(fw2, fw2_b, nff4);
  conv_embed_kernel<<<(VPAD * DMODEL / 4 + 255) / 256, 256, 0, stream>>>(embed, emb_b);

  embed_kernel<<<BT, 256, 0, stream>>>(tokens, embed, pos, h);

  const dim3 gqkv(3 * DMODEL / 128, BT / 128);
  const dim3 gff(DFFN / 128, BT / 128);
  const dim3 gwo(DMODEL / 128, BT / 128, 2);
  const dim3 gff2(DMODEL / 128, BT / 128, 4);
  const dim3 gv((BT / 128) * (VPAD / 128));  // 1-D, XCD-chunk swizzled

  for (int i = 0; i < NLAYER; ++i) {
    ln_kernel<<<BT, 256, 0, stream>>>(h, ln1g + i * DMODEL, ln1b + i * DMODEL, xn);

    gemm_bf16_nt<true, false, false, false, false, false, false>
        <<<gqkv, 256, 0, stream>>>(
            xn, wqkv_b + (size_t)i * 3 * DMODEL * DMODEL, nullptr,
            tmask + i * DMODEL, nullptr, nullptr, nullptr, 0, qb, kb, vb, BT,
            DMODEL, 3 * DMODEL, DMODEL);

    vtrans_kernel<<<dim3(SEQ / 64, NBH), 256, 0, stream>>>(vb, vt);

    fattn_kernel<<<dim3(SEQ / 64, NBH), 256, 0, stream>>>(qb, kb, vt, ab);

    // wo: split-K x2 -> partials, then reduce into h (residual)
    gemm_bf16_nt<false, false, false, false, false, false, true>
        <<<gwo, 256, 0, stream>>>(
            ab, wo_b + (size_t)i * DMODEL * DMODEL, nullptr, nullptr, nullptr,
            part, nullptr, DMODEL, nullptr, nullptr, nullptr, BT, DMODEL,
            DMODEL, DMODEL / 2);
    redk_kernel<2, false><<<BT, 256, 0, stream>>>(part, nullptr, h);

    ln_kernel<<<BT, 256, 0, stream>>>(h, ln2g + i * DMODEL, ln2b + i * DMODEL, xn);

    gemm_bf16_nt<false, true, true, false, true, false, false>
        <<<gff, 256, 0, stream>>>(
            xn, fw1_b + (size_t)i * DFFN * DMODEL, fb1 + i * DFFN, nullptr,
            nullptr, nullptr, ffb, DFFN, nullptr, nullptr, nullptr, BT, DMODEL,
            DFFN, DMODEL);

    // ff2: split-K x4 -> partials, then reduce (+bias) into h (residual)
    gemm_bf16_nt<false, false, false, false, false, false, true>
        <<<gff2, 256, 0, stream>>>(
            ffb, fw2_b + (size_t)i * DMODEL * DFFN, nullptr, nullptr, nullptr,
            part, nullptr, DMODEL, nullptr, nullptr, nullptr, BT, DFFN, DMODEL,
            DFFN / 4);
    redk_kernel<4, true><<<BT, 256, 0, stream>>>(part, fb2 + i * DMODEL, h);
  }

  ln_kernel<<<BT, 256, 0, stream>>>(h, lnfg, lnfb, xn);
  gemm_bf16_nt<false, false, false, false, false, true, false>
      <<<gv, 256, 0, stream>>>(
          xn, emb_b, nullptr, nullptr, nullptr, (float*)d_out, nullptr,
          VOCABSZ, nullptr, nullptr, nullptr, BT, DMODEL, VOCABSZ, DMODEL);
}

// Round 6
// 973.105 us; speedup vs baseline: 7.6213x; 1.0882x over previous
//
#include <hip/hip_runtime.h>
#include <math.h>

#define VOCABSZ 50257
#define VPAD 50304
#define DMODEL 768
#define NHEAD 12
#define NLAYER 4
#define SEQ 1024
#define BATCH 2
#define DHEAD 64
#define DFFN 3072
#define BT (BATCH * SEQ)
#define NBH (BATCH * NHEAD)

typedef __attribute__((ext_vector_type(8))) short bf16x8;
typedef __attribute__((ext_vector_type(4))) float f32x4;

__device__ __forceinline__ ushort f2bf(float f) {
  uint u = __builtin_bit_cast(uint, f);
  u = (u + 0x7fffu + ((u >> 16) & 1u)) >> 16;
  return (ushort)u;
}

__device__ __forceinline__ void gl_lds16(const ushort* g, ushort* l) {
  __builtin_amdgcn_global_load_lds(
      (const __attribute__((address_space(1))) void*)g,
      (__attribute__((address_space(3))) void*)l, 16, 0, 0);
}

// ------------------------------------------------------------- conversions
__global__ __launch_bounds__(256) void conv4_kernel(
    const float* __restrict__ src, ushort* __restrict__ dst, int n4) {
  int i = blockIdx.x * 256 + threadIdx.x;
  if (i >= n4) return;
  float4 v = reinterpret_cast<const float4*>(src)[i];
  reinterpret_cast<ushort4*>(dst)[i] =
      make_ushort4(f2bf(v.x), f2bf(v.y), f2bf(v.z), f2bf(v.w));
}

__global__ __launch_bounds__(256) void conv_qkv_kernel(
    const float* __restrict__ src, ushort* __restrict__ dst, int qoff4) {
  const int per4 = DMODEL * DMODEL / 4;
  int i = blockIdx.x * 256 + threadIdx.x;
  if (i >= NLAYER * per4) return;
  int layer = i / per4, rem = i % per4;
  float4 v = reinterpret_cast<const float4*>(src)[i];
  reinterpret_cast<ushort4*>(dst)[(size_t)layer * (3 * per4) + qoff4 + rem] =
      make_ushort4(f2bf(v.x), f2bf(v.y), f2bf(v.z), f2bf(v.w));
}

__global__ __launch_bounds__(256) void conv_embed_kernel(
    const float* __restrict__ emb, ushort* __restrict__ dst) {
  int i = blockIdx.x * 256 + threadIdx.x;
  if (i >= VPAD * DMODEL / 4) return;
  int row = (i * 4) / DMODEL;
  ushort4 o = make_ushort4(0, 0, 0, 0);
  if (row < VOCABSZ) {
    float4 v = reinterpret_cast<const float4*>(emb)[i];
    o = make_ushort4(f2bf(v.x), f2bf(v.y), f2bf(v.z), f2bf(v.w));
  }
  reinterpret_cast<ushort4*>(dst)[i] = o;
}

// ---------------------------------------------------------------- embedding
__global__ __launch_bounds__(256) void embed_kernel(
    const int* __restrict__ tok, const float* __restrict__ emb,
    const float* __restrict__ pos, float* __restrict__ h) {
  int row = blockIdx.x;
  int l = row % SEQ;
  int t = tok[row];
  int tid = threadIdx.x;
#pragma unroll
  for (int j = 0; j < 3; ++j) {
    int c = tid + j * 256;
    h[(size_t)row * DMODEL + c] =
        emb[(size_t)t * DMODEL + c] + pos[(size_t)l * DMODEL + c];
  }
}

// --------------------------------------- layernorm (+ fused split-K reduce)
// KS>0: h += (rbias?) + sum_z part[z]; write h back; then LN(h) -> o (bf16).
template <int KS, bool RBIAS>
__global__ __launch_bounds__(256) void ln_kernel(
    float* __restrict__ h, const float* __restrict__ part,
    const float* __restrict__ rb, const float* __restrict__ g,
    const float* __restrict__ bta, ushort* __restrict__ o) {
  __shared__ float red[8];
  int row = blockIdx.x;
  int tid = threadIdx.x;
  float* xr = h + (size_t)row * DMODEL;
  float v[3];
  float s = 0.f, sq = 0.f;
#pragma unroll
  for (int j = 0; j < 3; ++j) {
    int c = tid + j * 256;
    float a = xr[c];
    if (RBIAS) a += rb[c];
    if (KS > 0) {
#pragma unroll
      for (int z = 0; z < KS; ++z)
        a += part[(size_t)z * BT * DMODEL + (size_t)row * DMODEL + c];
      xr[c] = a;
    }
    v[j] = a;
    s += a;
    sq += a * a;
  }
#pragma unroll
  for (int off = 1; off < 64; off <<= 1) {
    s += __shfl_xor(s, off);
    sq += __shfl_xor(sq, off);
  }
  int wid = tid >> 6;
  if ((tid & 63) == 0) { red[wid * 2] = s; red[wid * 2 + 1] = sq; }
  __syncthreads();
  float S = red[0] + red[2] + red[4] + red[6];
  float SQ = red[1] + red[3] + red[5] + red[7];
  float mu = S * (1.0f / DMODEL);
  float var = SQ * (1.0f / DMODEL) - mu * mu;
  float r = rsqrtf(var + 1e-5f);
  ushort* orow = o + (size_t)row * DMODEL;
#pragma unroll
  for (int j = 0; j < 3; ++j) {
    int c = tid + j * 256;
    orow[c] = f2bf((v[j] - mu) * r * g[c] + bta[c]);
  }
}

// --------------------------------------------------- V transpose (per head)
__global__ __launch_bounds__(256) void vtrans_kernel(
    const ushort* __restrict__ v, ushort* __restrict__ vt) {
  __shared__ ushort t[64][65];
  int z = blockIdx.y, b = z / NHEAD, hh = z % NHEAD;
  int key0 = blockIdx.x * 64;
  int tid = threadIdx.x;
#pragma unroll
  for (int p = 0; p < 16; ++p) {
    int idx = tid + p * 256;
    int kk = idx >> 6, d = idx & 63;
    t[kk][d] = v[((size_t)(b * SEQ + key0 + kk)) * DMODEL + hh * DHEAD + d];
  }
  __syncthreads();
#pragma unroll
  for (int p = 0; p < 16; ++p) {
    int idx = tid + p * 256;
    int d = idx >> 6, kk = idx & 63;
    vt[((size_t)(z * 64 + d)) * SEQ + key0 + kk] = t[kk][d];
  }
}

// -------------------------------------------------------- flash attention
__global__ __launch_bounds__(256) void fattn_kernel(
    const ushort* __restrict__ q, const ushort* __restrict__ k,
    const ushort* __restrict__ vt, ushort* __restrict__ o) {
  __shared__ __align__(16) ushort Ks[64 * 64];
  __shared__ __align__(16) ushort Vs[64 * 64];
  __shared__ __align__(16) ushort Ps[4][16][80];
  const int z = blockIdx.y, b = z / NHEAD, hh = z % NHEAD;
  const int q0 = (gridDim.x - 1 - blockIdx.x) * 64;  // long blocks first
  const int tid = threadIdx.x, w = tid >> 6, l = tid & 63;
  const int fr = l & 15, ks = l >> 4;
  const int qrow = q0 + w * 16 + fr;
  const ushort* qp = q + (size_t)(b * SEQ + qrow) * DMODEL + hh * DHEAD;
  const bf16x8 qf0 = *reinterpret_cast<const bf16x8*>(qp + ks * 8);
  const bf16x8 qf1 = *reinterpret_cast<const bf16x8*>(qp + 32 + ks * 8);

  const int srow = w * 16 + (l >> 3);
  const int sslot = l & 7;

  f32x4 acc_o[4] = {};
  float mrun = -1e30f, lrun = 0.f;

  for (int k0 = 0; k0 <= q0; k0 += 64) {
#pragma unroll
    for (int c = 0; c < 2; ++c) {
      int r = srow + c * 8;
      int g = sslot ^ (r & 7);
      gl_lds16(k + (size_t)(b * SEQ + k0 + r) * DMODEL + hh * DHEAD + g * 8,
               Ks + (w * 16 + c * 8) * 64);
      gl_lds16(vt + (size_t)(z * 64 + r) * SEQ + k0 + g * 8,
               Vs + (w * 16 + c * 8) * 64);
    }
    __syncthreads();
    f32x4 acc_s[4] = {};
#pragma unroll
    for (int kstep = 0; kstep < 2; ++kstep) {
      const bf16x8 qf = kstep ? qf1 : qf0;
#pragma unroll
      for (int kb = 0; kb < 4; ++kb) {
        int ra = kb * 16 + fr;
        bf16x8 af = *reinterpret_cast<const bf16x8*>(
            Ks + ra * 64 + (((kstep * 4 + ks) ^ (ra & 7)) * 8));
        acc_s[kb] =
            __builtin_amdgcn_mfma_f32_16x16x32_bf16(af, qf, acc_s[kb], 0, 0, 0);
      }
    }
    const bool diag = (k0 == q0);
    float pm = -1e30f;
    float sv[4][4];
#pragma unroll
    for (int kb = 0; kb < 4; ++kb)
#pragma unroll
      for (int r = 0; r < 4; ++r) {
        float s = acc_s[kb][r];
        if (diag && (k0 + kb * 16 + ks * 4 + r > qrow)) s = -1e30f;
        sv[kb][r] = s;
        pm = fmaxf(pm, s);
      }
    pm = fmaxf(pm, __shfl_xor(pm, 16));
    pm = fmaxf(pm, __shfl_xor(pm, 32));
    float mnew = fmaxf(mrun, pm);
    float scale = __expf(mrun - mnew);
    float psum = 0.f;
#pragma unroll
    for (int kb = 0; kb < 4; ++kb) {
      float p0 = __expf(sv[kb][0] - mnew);
      float p1 = __expf(sv[kb][1] - mnew);
      float p2 = __expf(sv[kb][2] - mnew);
      float p3 = __expf(sv[kb][3] - mnew);
      psum += (p0 + p1) + (p2 + p3);
      *reinterpret_cast<ushort4*>(&Ps[w][fr][kb * 16 + ks * 4]) =
          make_ushort4(f2bf(p0), f2bf(p1), f2bf(p2), f2bf(p3));
    }
    psum += __shfl_xor(psum, 16);
    psum += __shfl_xor(psum, 32);
    lrun = lrun * scale + psum;
    mrun = mnew;
#pragma unroll
    for (int db = 0; db < 4; ++db) acc_o[db] *= scale;
#pragma unroll
    for (int kstep = 0; kstep < 2; ++kstep) {
      bf16x8 pf =
          *reinterpret_cast<const bf16x8*>(&Ps[w][fr][kstep * 32 + ks * 8]);
#pragma unroll
      for (int db = 0; db < 4; ++db) {
        int rd = db * 16 + fr;
        bf16x8 vf = *reinterpret_cast<const bf16x8*>(
            Vs + rd * 64 + (((kstep * 4 + ks) ^ (rd & 7)) * 8));
        acc_o[db] =
            __builtin_amdgcn_mfma_f32_16x16x32_bf16(vf, pf, acc_o[db], 0, 0, 0);
      }
    }
    __syncthreads();
  }
  float rinv = 1.0f / lrun;
#pragma unroll
  for (int db = 0; db < 4; ++db) {
    ushort4 o4 =
        make_ushort4(f2bf(acc_o[db][0] * rinv), f2bf(acc_o[db][1] * rinv),
                     f2bf(acc_o[db][2] * rinv), f2bf(acc_o[db][3] * rinv));
    *reinterpret_cast<ushort4*>(o + (size_t)(b * SEQ + qrow) * DMODEL +
                                hh * DHEAD + db * 16 + ks * 4) = o4;
  }
}

// ------------------------------------------------------- bf16 MFMA NT GEMM
// C[m,n] = sum_k A[m,k]*B[n,k]. Double-buffered LDS, prefetch-before-compute
// (T3 2-phase minimum). SWZ: XCD-chunked 1-D grid. PART: split-K partials.
template <bool QKV, bool BIAS, bool GELU, bool RES, bool OUTBF, bool SWZ,
          bool PART>
__global__ __launch_bounds__(256) void gemm_bf16_nt(
    const ushort* __restrict__ A, const ushort* __restrict__ B,
    const float* __restrict__ bias, const int* __restrict__ tmask,
    const float* __restrict__ res, float* __restrict__ Cf,
    ushort* __restrict__ Cb, int ldc, ushort* __restrict__ qb,
    ushort* __restrict__ kb, ushort* __restrict__ vb, int M, int K, int Nreal,
    int kchunk) {
  __shared__ __align__(16) ushort As[2][128 * 32];
  __shared__ __align__(16) ushort Bs[2][128 * 32];
  int bnx, bmy;
  if (SWZ) {
    int bid = blockIdx.x;
    int chunk = gridDim.x >> 3;
    int wgid = (bid & 7) * chunk + (bid >> 3);
    int mb = M >> 7;
    bmy = wgid % mb;
    bnx = wgid / mb;
  } else {
    bnx = blockIdx.x;
    bmy = blockIdx.y;
  }
  const int m0 = bmy * 128, n0 = bnx * 128;
  const int kbeg = PART ? blockIdx.z * kchunk : 0;
  const int kend = PART ? kbeg + kchunk : K;
  if (PART) Cf += (size_t)blockIdx.z * M * ldc;
  const int tid = threadIdx.x;
  const int w = tid >> 6, l = tid & 63;
  const int wr = w >> 1, wc = w & 1;
  const int fr = l & 15, ks = l >> 4;

  const int seg0 = w * 2, seg1 = w * 2 + 1;
  const int srow0 = seg0 * 16 + (l >> 2);
  const int srow1 = seg1 * 16 + (l >> 2);
  const int koff0 = (((l & 3) ^ ((srow0 >> 1) & 3))) * 8;
  const int koff1 = (((l & 3) ^ ((srow1 >> 1) & 3))) * 8;
  const ushort* A0 = A + (size_t)(m0 + srow0) * K + koff0;
  const ushort* A1 = A + (size_t)(m0 + srow1) * K + koff1;
  const ushort* B0 = B + (size_t)(n0 + srow0) * K + koff0;
  const ushort* B1 = B + (size_t)(n0 + srow1) * K + koff1;

  int aoff[4], boff[4];
#pragma unroll
  for (int i = 0; i < 4; ++i) {
    int ra = wr * 64 + i * 16 + fr;
    aoff[i] = ra * 32 + ((ks ^ ((ra >> 1) & 3)) * 8);
    int rb = wc * 64 + i * 16 + fr;
    boff[i] = rb * 32 + ((ks ^ ((rb >> 1) & 3)) * 8);
  }

  // prologue: stage tile 0 into buffer 0
  gl_lds16(A0 + kbeg, &As[0][seg0 * 512]);
  gl_lds16(A1 + kbeg, &As[0][seg1 * 512]);
  gl_lds16(B0 + kbeg, &Bs[0][seg0 * 512]);
  gl_lds16(B1 + kbeg, &Bs[0][seg1 * 512]);
  __syncthreads();

  f32x4 acc[4][4] = {};
  int cur = 0;
  for (int k0 = kbeg; k0 < kend; k0 += 32) {
    const int nxt = k0 + 32;
    if (nxt < kend) {  // prefetch next tile into the other buffer
      gl_lds16(A0 + nxt, &As[cur ^ 1][seg0 * 512]);
      gl_lds16(A1 + nxt, &As[cur ^ 1][seg1 * 512]);
      gl_lds16(B0 + nxt, &Bs[cur ^ 1][seg0 * 512]);
      gl_lds16(B1 + nxt, &Bs[cur ^ 1][seg1 * 512]);
    }
    bf16x8 af[4], bfr[4];
#pragma unroll
    for (int i = 0; i < 4; ++i)
      af[i] = *reinterpret_cast<const bf16x8*>(&As[cur][aoff[i]]);
#pragma unroll
    for (int i = 0; i < 4; ++i)
      bfr[i] = *reinterpret_cast<const bf16x8*>(&Bs[cur][boff[i]]);
#pragma unroll
    for (int mi = 0; mi < 4; ++mi)
#pragma unroll
      for (int nj = 0; nj < 4; ++nj)
        acc[mi][nj] = __builtin_amdgcn_mfma_f32_16x16x32_bf16(
            af[mi], bfr[nj], acc[mi][nj], 0, 0, 0);
    __syncthreads();  // drains prefetch (overlapped with MFMA) + barrier
    cur ^= 1;
  }

#pragma unroll
  for (int mi = 0; mi < 4; ++mi) {
#pragma unroll
    for (int nj = 0; nj < 4; ++nj) {
      int n = n0 + wc * 64 + nj * 16 + fr;
      if (n < Nreal) {
#pragma unroll
        for (int r = 0; r < 4; ++r) {
          int m = m0 + wr * 64 + mi * 16 + ks * 4 + r;
          float v = acc[mi][nj][r];
          if (PART) {
            Cf[(size_t)m * ldc + n] = v;
          } else if (QKV) {
            if (n < DMODEL) {
              v *= (1.0f - 0.5f * (float)tmask[n]) * 0.125f;
              qb[(size_t)m * DMODEL + n] = f2bf(v);
            } else if (n < 2 * DMODEL) {
              kb[(size_t)m * DMODEL + (n - DMODEL)] = f2bf(v);
            } else {
              vb[(size_t)m * DMODEL + (n - 2 * DMODEL)] = f2bf(v);
            }
          } else {
            if (BIAS) v += bias[n];
            if (GELU) v = 0.5f * v * (1.0f + erff(v * 0.70710678118f));
            if (RES) v += res[(size_t)m * ldc + n];
            if (OUTBF)
              Cb[(size_t)m * ldc + n] = f2bf(v);
            else
              Cf[(size_t)m * ldc + n] = v;
          }
        }
      }
    }
  }
}

// ---------------------------------------------------------------- launch
extern "C" void kernel_launch(void* const* d_in, const int* in_sizes, int n_in,
                              void* d_out, int out_size, void* d_ws,
                              size_t ws_size, hipStream_t stream) {
  const int* tokens = (const int*)d_in[0];
  const int* tmask = (const int*)d_in[1];
  const float* embed = (const float*)d_in[2];
  const float* pos = (const float*)d_in[3];
  const float* wq = (const float*)d_in[4];
  const float* wk = (const float*)d_in[5];
  const float* wv = (const float*)d_in[6];
  const float* wo = (const float*)d_in[7];
  const float* ln1g = (const float*)d_in[8];
  const float* ln1b = (const float*)d_in[9];
  const float* ln2g = (const float*)d_in[10];
  const float* ln2b = (const float*)d_in[11];
  const float* fw1 = (const float*)d_in[12];
  const float* fb1 = (const float*)d_in[13];
  const float* fw2 = (const float*)d_in[14];
  const float* fb2 = (const float*)d_in[15];
  const float* lnfg = (const float*)d_in[16];
  const float* lnfb = (const float*)d_in[17];

  char* wp = (char*)d_ws;
  auto alloc = [&](size_t bytes) {
    void* p = wp;
    wp += (bytes + 255) & ~(size_t)255;
    return p;
  };
  float* h = (float*)alloc((size_t)BT * DMODEL * 4);
  float* part = (float*)alloc((size_t)4 * BT * DMODEL * 4);
  ushort* qb = (ushort*)alloc((size_t)BT * DMODEL * 2);
  ushort* kb = (ushort*)alloc((size_t)BT * DMODEL * 2);
  ushort* vb = (ushort*)alloc((size_t)BT * DMODEL * 2);
  ushort* vt = (ushort*)alloc((size_t)NBH * DHEAD * SEQ * 2);
  ushort* xn = (ushort*)alloc((size_t)BT * DMODEL * 2);
  ushort* ab = (ushort*)alloc((size_t)BT * DMODEL * 2);
  ushort* ffb = (ushort*)alloc((size_t)BT * DFFN * 2);
  ushort* wqkv_b = (ushort*)alloc((size_t)NLAYER * 3 * DMODEL * DMODEL * 2);
  ushort* wo_b = (ushort*)alloc((size_t)NLAYER * DMODEL * DMODEL * 2);
  ushort* fw1_b = (ushort*)alloc((size_t)NLAYER * DFFN * DMODEL * 2);
  ushort* fw2_b = (ushort*)alloc((size_t)NLAYER * DMODEL * DFFN * 2);
  ushort* emb_b = (ushort*)alloc((size_t)VPAD * DMODEL * 2);

  const int per4 = DMODEL * DMODEL / 4;
  conv_qkv_kernel<<<(NLAYER * per4 + 255) / 256, 256, 0, stream>>>(wq, wqkv_b, 0);
  conv_qkv_kernel<<<(NLAYER * per4 + 255) / 256, 256, 0, stream>>>(wk, wqkv_b, per4);
  conv_qkv_kernel<<<(NLAYER * per4 + 255) / 256, 256, 0, stream>>>(wv, wqkv_b, 2 * per4);
  conv4_kernel<<<(NLAYER * per4 + 255) / 256, 256, 0, stream>>>(wo, wo_b, NLAYER * per4);
  const int nff4 = NLAYER * DFFN * DMODEL / 4;
  conv4_kernel<<<(nff4 + 255) / 256, 256, 0, stream>>>(fw1, fw1_b, nff4);
  conv4_kernel<<<(nff4 + 255) / 256, 256, 0, stream>>>(fw2, fw2_b, nff4);
  conv_embed_kernel<<<(VPAD * DMODEL / 4 + 255) / 256, 256, 0, stream>>>(embed, emb_b);

  embed_kernel<<<BT, 256, 0, stream>>>(tokens, embed, pos, h);

  const dim3 gqkv(3 * DMODEL / 128, BT / 128);
  const dim3 gff(DFFN / 128, BT / 128);
  const dim3 gwo(DMODEL / 128, BT / 128, 2);
  const dim3 gff2(DMODEL / 128, BT / 128, 4);
  const dim3 gv((BT / 128) * (VPAD / 128));  // 1-D, XCD-chunk swizzled

  for (int i = 0; i < NLAYER; ++i) {
    // ln1: layer 0 plain; layers 1..3 fused with previous ff2 reduce (+fb2)
    if (i == 0)
      ln_kernel<0, false><<<BT, 256, 0, stream>>>(
          h, nullptr, nullptr, ln1g + i * DMODEL, ln1b + i * DMODEL, xn);
    else
      ln_kernel<4, true><<<BT, 256, 0, stream>>>(
          h, part, fb2 + (i - 1) * DMODEL, ln1g + i * DMODEL,
          ln1b + i * DMODEL, xn);

    gemm_bf16_nt<true, false, false, false, false, false, false>
        <<<gqkv, 256, 0, stream>>>(
            xn, wqkv_b + (size_t)i * 3 * DMODEL * DMODEL, nullptr,
            tmask + i * DMODEL, nullptr, nullptr, nullptr, 0, qb, kb, vb, BT,
            DMODEL, 3 * DMODEL, DMODEL);

    vtrans_kernel<<<dim3(SEQ / 64, NBH), 256, 0, stream>>>(vb, vt);

    fattn_kernel<<<dim3(SEQ / 64, NBH), 256, 0, stream>>>(qb, kb, vt, ab);

    // wo: split-K x2 -> partials (reduced inside ln2)
    gemm_bf16_nt<false, false, false, false, false, false, true>
        <<<gwo, 256, 0, stream>>>(
            ab, wo_b + (size_t)i * DMODEL * DMODEL, nullptr, nullptr, nullptr,
            part, nullptr, DMODEL, nullptr, nullptr, nullptr, BT, DMODEL,
            DMODEL, DMODEL / 2);

    // ln2 fused with wo reduce (no bias)
    ln_kernel<2, false><<<BT, 256, 0, stream>>>(
        h, part, nullptr, ln2g + i * DMODEL, ln2b + i * DMODEL, xn);

    gemm_bf16_nt<false, true, true, false, true, false, false>
        <<<gff, 256, 0, stream>>>(
            xn, fw1_b + (size_t)i * DFFN * DMODEL, fb1 + i * DFFN, nullptr,
            nullptr, nullptr, ffb, DFFN, nullptr, nullptr, nullptr, BT, DMODEL,
            DFFN, DMODEL);

    // ff2: split-K x4 -> partials (reduced inside next ln1 / final lnf)
    gemm_bf16_nt<false, false, false, false, false, false, true>
        <<<gff2, 256, 0, stream>>>(
            ffb, fw2_b + (size_t)i * DMODEL * DFFN, nullptr, nullptr, nullptr,
            part, nullptr, DMODEL, nullptr, nullptr, nullptr, BT, DFFN, DMODEL,
            DFFN / 4);
  }

  // final LN fused with layer-3 ff2 reduce (+fb2)
  ln_kernel<4, true><<<BT, 256, 0, stream>>>(
      h, part, fb2 + (NLAYER - 1) * DMODEL, lnfg, lnfb, xn);

  gemm_bf16_nt<false, false, false, false, false, true, false>
      <<<gv, 256, 0, stream>>>(
          xn, emb_b, nullptr, nullptr, nullptr, (float*)d_out, nullptr,
          VOCABSZ, nullptr, nullptr, nullptr, BT, DMODEL, VOCABSZ, DMODEL);
}

// Round 7
// 941.659 us; speedup vs baseline: 7.8758x; 1.0334x over previous
//
#include <hip/hip_runtime.h>
#include <math.h>

#define VOCABSZ 50257
#define VPAD 50432
#define DMODEL 768
#define NHEAD 12
#define NLAYER 4
#define SEQ 1024
#define BATCH 2
#define DHEAD 64
#define DFFN 3072
#define BT (BATCH * SEQ)
#define NBH (BATCH * NHEAD)

typedef __attribute__((ext_vector_type(8))) short bf16x8;
typedef __attribute__((ext_vector_type(4))) float f32x4;

__device__ __forceinline__ ushort f2bf(float f) {
  uint u = __builtin_bit_cast(uint, f);
  u = (u + 0x7fffu + ((u >> 16) & 1u)) >> 16;
  return (ushort)u;
}

__device__ __forceinline__ void gl_lds16(const ushort* g, ushort* l) {
  __builtin_amdgcn_global_load_lds(
      (const __attribute__((address_space(1))) void*)g,
      (__attribute__((address_space(3))) void*)l, 16, 0, 0);
}

// ------------------------------------------------------------- conversions
__global__ __launch_bounds__(256) void conv4_kernel(
    const float* __restrict__ src, ushort* __restrict__ dst, int n4) {
  int i = blockIdx.x * 256 + threadIdx.x;
  if (i >= n4) return;
  float4 v = reinterpret_cast<const float4*>(src)[i];
  reinterpret_cast<ushort4*>(dst)[i] =
      make_ushort4(f2bf(v.x), f2bf(v.y), f2bf(v.z), f2bf(v.w));
}

__global__ __launch_bounds__(256) void conv_qkv_kernel(
    const float* __restrict__ src, ushort* __restrict__ dst, int qoff4) {
  const int per4 = DMODEL * DMODEL / 4;
  int i = blockIdx.x * 256 + threadIdx.x;
  if (i >= NLAYER * per4) return;
  int layer = i / per4, rem = i % per4;
  float4 v = reinterpret_cast<const float4*>(src)[i];
  reinterpret_cast<ushort4*>(dst)[(size_t)layer * (3 * per4) + qoff4 + rem] =
      make_ushort4(f2bf(v.x), f2bf(v.y), f2bf(v.z), f2bf(v.w));
}

__global__ __launch_bounds__(256) void conv_embed_kernel(
    const float* __restrict__ emb, ushort* __restrict__ dst) {
  int i = blockIdx.x * 256 + threadIdx.x;
  if (i >= VPAD * DMODEL / 4) return;
  int row = (i * 4) / DMODEL;
  ushort4 o = make_ushort4(0, 0, 0, 0);
  if (row < VOCABSZ) {
    float4 v = reinterpret_cast<const float4*>(emb)[i];
    o = make_ushort4(f2bf(v.x), f2bf(v.y), f2bf(v.z), f2bf(v.w));
  }
  reinterpret_cast<ushort4*>(dst)[i] = o;
}

// ---------------------------------------------------------------- embedding
__global__ __launch_bounds__(256) void embed_kernel(
    const int* __restrict__ tok, const float* __restrict__ emb,
    const float* __restrict__ pos, float* __restrict__ h) {
  int row = blockIdx.x;
  int l = row % SEQ;
  int t = tok[row];
  int tid = threadIdx.x;
#pragma unroll
  for (int j = 0; j < 3; ++j) {
    int c = tid + j * 256;
    h[(size_t)row * DMODEL + c] =
        emb[(size_t)t * DMODEL + c] + pos[(size_t)l * DMODEL + c];
  }
}

// --------------------------------------- layernorm (+ fused split-K reduce)
template <int KS, bool RBIAS>
__global__ __launch_bounds__(256) void ln_kernel(
    float* __restrict__ h, const float* __restrict__ part,
    const float* __restrict__ rb, const float* __restrict__ g,
    const float* __restrict__ bta, ushort* __restrict__ o) {
  __shared__ float red[8];
  int row = blockIdx.x;
  int tid = threadIdx.x;
  float* xr = h + (size_t)row * DMODEL;
  float v[3];
  float s = 0.f, sq = 0.f;
#pragma unroll
  for (int j = 0; j < 3; ++j) {
    int c = tid + j * 256;
    float a = xr[c];
    if (RBIAS) a += rb[c];
    if (KS > 0) {
#pragma unroll
      for (int z = 0; z < KS; ++z)
        a += part[(size_t)z * BT * DMODEL + (size_t)row * DMODEL + c];
      xr[c] = a;
    }
    v[j] = a;
    s += a;
    sq += a * a;
  }
#pragma unroll
  for (int off = 1; off < 64; off <<= 1) {
    s += __shfl_xor(s, off);
    sq += __shfl_xor(sq, off);
  }
  int wid = tid >> 6;
  if ((tid & 63) == 0) { red[wid * 2] = s; red[wid * 2 + 1] = sq; }
  __syncthreads();
  float S = red[0] + red[2] + red[4] + red[6];
  float SQ = red[1] + red[3] + red[5] + red[7];
  float mu = S * (1.0f / DMODEL);
  float var = SQ * (1.0f / DMODEL) - mu * mu;
  float r = rsqrtf(var + 1e-5f);
  ushort* orow = o + (size_t)row * DMODEL;
#pragma unroll
  for (int j = 0; j < 3; ++j) {
    int c = tid + j * 256;
    orow[c] = f2bf((v[j] - mu) * r * g[c] + bta[c]);
  }
}

// -------------------------------------------------------- flash attention
__global__ __launch_bounds__(256) void fattn_kernel(
    const ushort* __restrict__ q, const ushort* __restrict__ k,
    const ushort* __restrict__ vt, ushort* __restrict__ o) {
  __shared__ __align__(16) ushort Ks[64 * 64];
  __shared__ __align__(16) ushort Vs[64 * 64];
  __shared__ __align__(16) ushort Ps[4][16][80];
  const int z = blockIdx.y, b = z / NHEAD, hh = z % NHEAD;
  const int q0 = (gridDim.x - 1 - blockIdx.x) * 64;  // long blocks first
  const int tid = threadIdx.x, w = tid >> 6, l = tid & 63;
  const int fr = l & 15, ks = l >> 4;
  const int qrow = q0 + w * 16 + fr;
  const ushort* qp = q + (size_t)(b * SEQ + qrow) * DMODEL + hh * DHEAD;
  const bf16x8 qf0 = *reinterpret_cast<const bf16x8*>(qp + ks * 8);
  const bf16x8 qf1 = *reinterpret_cast<const bf16x8*>(qp + 32 + ks * 8);

  const int srow = w * 16 + (l >> 3);
  const int sslot = l & 7;

  f32x4 acc_o[4] = {};
  float mrun = -1e30f, lrun = 0.f;

  for (int k0 = 0; k0 <= q0; k0 += 64) {
#pragma unroll
    for (int c = 0; c < 2; ++c) {
      int r = srow + c * 8;
      int g = sslot ^ (r & 7);
      gl_lds16(k + (size_t)(b * SEQ + k0 + r) * DMODEL + hh * DHEAD + g * 8,
               Ks + (w * 16 + c * 8) * 64);
      gl_lds16(vt + (size_t)(z * 64 + r) * SEQ + k0 + g * 8,
               Vs + (w * 16 + c * 8) * 64);
    }
    __syncthreads();
    f32x4 acc_s[4] = {};
#pragma unroll
    for (int kstep = 0; kstep < 2; ++kstep) {
      const bf16x8 qf = kstep ? qf1 : qf0;
#pragma unroll
      for (int kb = 0; kb < 4; ++kb) {
        int ra = kb * 16 + fr;
        bf16x8 af = *reinterpret_cast<const bf16x8*>(
            Ks + ra * 64 + (((kstep * 4 + ks) ^ (ra & 7)) * 8));
        acc_s[kb] =
            __builtin_amdgcn_mfma_f32_16x16x32_bf16(af, qf, acc_s[kb], 0, 0, 0);
      }
    }
    const bool diag = (k0 == q0);
    float pm = -1e30f;
    float sv[4][4];
#pragma unroll
    for (int kb = 0; kb < 4; ++kb)
#pragma unroll
      for (int r = 0; r < 4; ++r) {
        float s = acc_s[kb][r];
        if (diag && (k0 + kb * 16 + ks * 4 + r > qrow)) s = -1e30f;
        sv[kb][r] = s;
        pm = fmaxf(pm, s);
      }
    pm = fmaxf(pm, __shfl_xor(pm, 16));
    pm = fmaxf(pm, __shfl_xor(pm, 32));
    float mnew = fmaxf(mrun, pm);
    float scale = __expf(mrun - mnew);
    float psum = 0.f;
#pragma unroll
    for (int kb = 0; kb < 4; ++kb) {
      float p0 = __expf(sv[kb][0] - mnew);
      float p1 = __expf(sv[kb][1] - mnew);
      float p2 = __expf(sv[kb][2] - mnew);
      float p3 = __expf(sv[kb][3] - mnew);
      psum += (p0 + p1) + (p2 + p3);
      *reinterpret_cast<ushort4*>(&Ps[w][fr][kb * 16 + ks * 4]) =
          make_ushort4(f2bf(p0), f2bf(p1), f2bf(p2), f2bf(p3));
    }
    psum += __shfl_xor(psum, 16);
    psum += __shfl_xor(psum, 32);
    lrun = lrun * scale + psum;
    mrun = mnew;
#pragma unroll
    for (int db = 0; db < 4; ++db) acc_o[db] *= scale;
#pragma unroll
    for (int kstep = 0; kstep < 2; ++kstep) {
      bf16x8 pf =
          *reinterpret_cast<const bf16x8*>(&Ps[w][fr][kstep * 32 + ks * 8]);
#pragma unroll
      for (int db = 0; db < 4; ++db) {
        int rd = db * 16 + fr;
        bf16x8 vf = *reinterpret_cast<const bf16x8*>(
            Vs + rd * 64 + (((kstep * 4 + ks) ^ (rd & 7)) * 8));
        acc_o[db] =
            __builtin_amdgcn_mfma_f32_16x16x32_bf16(vf, pf, acc_o[db], 0, 0, 0);
      }
    }
    __syncthreads();
  }
  float rinv = 1.0f / lrun;
#pragma unroll
  for (int db = 0; db < 4; ++db) {
    ushort4 o4 =
        make_ushort4(f2bf(acc_o[db][0] * rinv), f2bf(acc_o[db][1] * rinv),
                     f2bf(acc_o[db][2] * rinv), f2bf(acc_o[db][3] * rinv));
    *reinterpret_cast<ushort4*>(o + (size_t)(b * SEQ + qrow) * DMODEL +
                                hh * DHEAD + db * 16 + ks * 4) = o4;
  }
}

// ------------------------------------------------------- bf16 MFMA NT GEMM
// 128x128 tile, BK=32, dbuf. QKV epilogue writes q,k and V transposed to vt.
template <bool QKV, bool BIAS, bool GELU, bool RES, bool OUTBF, bool PART>
__global__ __launch_bounds__(256) void gemm_bf16_nt(
    const ushort* __restrict__ A, const ushort* __restrict__ B,
    const float* __restrict__ bias, const int* __restrict__ tmask,
    const float* __restrict__ res, float* __restrict__ Cf,
    ushort* __restrict__ Cb, int ldc, ushort* __restrict__ qb,
    ushort* __restrict__ kb, ushort* __restrict__ vt, int M, int K, int Nreal,
    int kchunk) {
  __shared__ __align__(16) ushort As[2][128 * 32];
  __shared__ __align__(16) ushort Bs[2][128 * 32];
  const int m0 = blockIdx.y * 128, n0 = blockIdx.x * 128;
  const int kbeg = PART ? blockIdx.z * kchunk : 0;
  const int kend = PART ? kbeg + kchunk : K;
  if (PART) Cf += (size_t)blockIdx.z * M * ldc;
  const int tid = threadIdx.x;
  const int w = tid >> 6, l = tid & 63;
  const int wr = w >> 1, wc = w & 1;
  const int fr = l & 15, ks = l >> 4;

  const int seg0 = w * 2, seg1 = w * 2 + 1;
  const int srow0 = seg0 * 16 + (l >> 2);
  const int srow1 = seg1 * 16 + (l >> 2);
  const int koff0 = (((l & 3) ^ ((srow0 >> 1) & 3))) * 8;
  const int koff1 = (((l & 3) ^ ((srow1 >> 1) & 3))) * 8;
  const ushort* A0 = A + (size_t)(m0 + srow0) * K + koff0;
  const ushort* A1 = A + (size_t)(m0 + srow1) * K + koff1;
  const ushort* B0 = B + (size_t)(n0 + srow0) * K + koff0;
  const ushort* B1 = B + (size_t)(n0 + srow1) * K + koff1;

  int aoff[4], boff[4];
#pragma unroll
  for (int i = 0; i < 4; ++i) {
    int ra = wr * 64 + i * 16 + fr;
    aoff[i] = ra * 32 + ((ks ^ ((ra >> 1) & 3)) * 8);
    int rb = wc * 64 + i * 16 + fr;
    boff[i] = rb * 32 + ((ks ^ ((rb >> 1) & 3)) * 8);
  }

  gl_lds16(A0 + kbeg, &As[0][seg0 * 512]);
  gl_lds16(A1 + kbeg, &As[0][seg1 * 512]);
  gl_lds16(B0 + kbeg, &Bs[0][seg0 * 512]);
  gl_lds16(B1 + kbeg, &Bs[0][seg1 * 512]);
  __syncthreads();

  f32x4 acc[4][4] = {};
  int cur = 0;
  for (int k0 = kbeg; k0 < kend; k0 += 32) {
    const int nxt = k0 + 32;
    if (nxt < kend) {
      gl_lds16(A0 + nxt, &As[cur ^ 1][seg0 * 512]);
      gl_lds16(A1 + nxt, &As[cur ^ 1][seg1 * 512]);
      gl_lds16(B0 + nxt, &Bs[cur ^ 1][seg0 * 512]);
      gl_lds16(B1 + nxt, &Bs[cur ^ 1][seg1 * 512]);
    }
    bf16x8 af[4], bfr[4];
#pragma unroll
    for (int i = 0; i < 4; ++i)
      af[i] = *reinterpret_cast<const bf16x8*>(&As[cur][aoff[i]]);
#pragma unroll
    for (int i = 0; i < 4; ++i)
      bfr[i] = *reinterpret_cast<const bf16x8*>(&Bs[cur][boff[i]]);
#pragma unroll
    for (int mi = 0; mi < 4; ++mi)
#pragma unroll
      for (int nj = 0; nj < 4; ++nj)
        acc[mi][nj] = __builtin_amdgcn_mfma_f32_16x16x32_bf16(
            af[mi], bfr[nj], acc[mi][nj], 0, 0, 0);
    __syncthreads();
    cur ^= 1;
  }

#pragma unroll
  for (int mi = 0; mi < 4; ++mi) {
#pragma unroll
    for (int nj = 0; nj < 4; ++nj) {
      int n = n0 + wc * 64 + nj * 16 + fr;
      if (n < Nreal) {
        if (PART) {
#pragma unroll
          for (int r = 0; r < 4; ++r) {
            int m = m0 + wr * 64 + mi * 16 + ks * 4 + r;
            Cf[(size_t)m * ldc + n] = acc[mi][nj][r];
          }
        } else if (QKV) {
          if (n < DMODEL) {
            float sc = (1.0f - 0.5f * (float)tmask[n]) * 0.125f;
#pragma unroll
            for (int r = 0; r < 4; ++r) {
              int m = m0 + wr * 64 + mi * 16 + ks * 4 + r;
              qb[(size_t)m * DMODEL + n] = f2bf(acc[mi][nj][r] * sc);
            }
          } else if (n < 2 * DMODEL) {
#pragma unroll
            for (int r = 0; r < 4; ++r) {
              int m = m0 + wr * 64 + mi * 16 + ks * 4 + r;
              kb[(size_t)m * DMODEL + (n - DMODEL)] = f2bf(acc[mi][nj][r]);
            }
          } else {
            // V written head-transposed: vt[(b*H+h)*64+d][key]
            int d = n - 2 * DMODEL;
            int key = (m0 & (SEQ - 1)) + wr * 64 + mi * 16 + ks * 4;
            size_t zr = (size_t)((m0 >> 10) * NHEAD + (d >> 6)) * 64 + (d & 63);
            ushort4 p4 = make_ushort4(
                f2bf(acc[mi][nj][0]), f2bf(acc[mi][nj][1]),
                f2bf(acc[mi][nj][2]), f2bf(acc[mi][nj][3]));
            *reinterpret_cast<ushort4*>(vt + zr * SEQ + key) = p4;
          }
        } else {
#pragma unroll
          for (int r = 0; r < 4; ++r) {
            int m = m0 + wr * 64 + mi * 16 + ks * 4 + r;
            float v = acc[mi][nj][r];
            if (BIAS) v += bias[n];
            if (GELU) v = 0.5f * v * (1.0f + erff(v * 0.70710678118f));
            if (RES) v += res[(size_t)m * ldc + n];
            if (OUTBF)
              Cb[(size_t)m * ldc + n] = f2bf(v);
            else
              Cf[(size_t)m * ldc + n] = v;
          }
        }
      }
    }
  }
}

// -------------------------------------------- LM head: 256x256 deep pipeline
// 8 waves (2M x 4N), BK=32, 4-deep LDS ring, counted vmcnt, setprio phases.
__global__ __launch_bounds__(512, 2) void gemm_lmhead(
    const ushort* __restrict__ A, const ushort* __restrict__ B,
    float* __restrict__ C) {
  __shared__ __align__(16) ushort As[4][256 * 32];
  __shared__ __align__(16) ushort Bs[4][256 * 32];
  const int K = DMODEL;
  const int NT = K / 32;  // 24

  const int bid = blockIdx.x;
  const int chunk = gridDim.x >> 3;  // 197 (grid multiple of 8)
  const int wgid = (bid & 7) * chunk + (bid >> 3);
  const int m0 = (wgid & 7) * 256;   // m fast -> B-panel reuse within XCD
  const int n0 = (wgid >> 3) * 256;

  const int tid = threadIdx.x;
  const int w = tid >> 6, l = tid & 63;
  const int wr = w >> 2, wc = w & 3;
  const int fr = l & 15, ks = l >> 4;

  // staging: one call = 512 thr x 16B = 128 rows x 32k; pre-swizzled source
  const int g8 = ((l & 3) ^ ((l >> 3) & 3)) * 8;
  const int sr = w * 16 + (l >> 2);  // 0..127 within call
  // fragment LDS offsets (swizzled read: slot ^= (row>>1)&3 == (fr>>1)&3)
  const int aswz = (ks ^ ((fr >> 1) & 3)) * 8;
  int aoff[8], boff[4];
#pragma unroll
  for (int mi = 0; mi < 8; ++mi)
    aoff[mi] = (wr * 128 + mi * 16 + fr) * 32 + aswz;
#pragma unroll
  for (int nj = 0; nj < 4; ++nj)
    boff[nj] = (wc * 64 + nj * 16 + fr) * 32 + aswz;

  auto stA = [&](int t, int c) {
    gl_lds16(A + (size_t)(m0 + c * 128 + sr) * K + t * 32 + g8,
             &As[t & 3][(c * 128 + w * 16) * 32]);
  };
  auto stB = [&](int t, int c) {
    gl_lds16(B + (size_t)(n0 + c * 128 + sr) * K + t * 32 + g8,
             &Bs[t & 3][(c * 128 + w * 16) * 32]);
  };

  // prologue: stage tiles 0,1,2 (12 loads); wait tile 0 (leave 8 in flight)
#pragma unroll
  for (int pt = 0; pt < 3; ++pt) {
    stA(pt, 0); stA(pt, 1); stB(pt, 0); stB(pt, 1);
  }
  asm volatile("s_waitcnt vmcnt(8)" ::: "memory");
  __builtin_amdgcn_s_barrier();

  f32x4 acc[8][4] = {};
  for (int t = 0; t < NT; ++t) {
    const ushort* Asl = &As[t & 3][0];
    const ushort* Bsl = &Bs[t & 3][0];
    const bool pf = (t + 3 < NT);
    bf16x8 bfr[4], af[4];
    // ---- phase 0: B frags + A rows 0..63 of wave half; stage A of t+3
#pragma unroll
    for (int nj = 0; nj < 4; ++nj)
      bfr[nj] = *reinterpret_cast<const bf16x8*>(Bsl + boff[nj]);
#pragma unroll
    for (int mi = 0; mi < 4; ++mi)
      af[mi] = *reinterpret_cast<const bf16x8*>(Asl + aoff[mi]);
    if (pf) { stA(t + 3, 0); stA(t + 3, 1); }
    __builtin_amdgcn_s_barrier();
    __builtin_amdgcn_s_setprio(1);
#pragma unroll
    for (int mi = 0; mi < 4; ++mi)
#pragma unroll
      for (int nj = 0; nj < 4; ++nj)
        acc[mi][nj] = __builtin_amdgcn_mfma_f32_16x16x32_bf16(
            af[mi], bfr[nj], acc[mi][nj], 0, 0, 0);
    __builtin_amdgcn_s_setprio(0);
    __builtin_amdgcn_s_barrier();
    // ---- phase 1: A rows 64..127; stage B of t+3
#pragma unroll
    for (int mi = 0; mi < 4; ++mi)
      af[mi] = *reinterpret_cast<const bf16x8*>(Asl + aoff[mi + 4]);
    if (pf) { stB(t + 3, 0); stB(t + 3, 1); }
    __builtin_amdgcn_s_barrier();
    __builtin_amdgcn_s_setprio(1);
#pragma unroll
    for (int mi = 0; mi < 4; ++mi)
#pragma unroll
      for (int nj = 0; nj < 4; ++nj)
        acc[mi + 4][nj] = __builtin_amdgcn_mfma_f32_16x16x32_bf16(
            af[mi], bfr[nj], acc[mi + 4][nj], 0, 0, 0);
    __builtin_amdgcn_s_setprio(0);
    // ---- tile gate: ensure t+1 resident; keep newer loads in flight
    if (t + 3 < NT)
      asm volatile("s_waitcnt vmcnt(8)" ::: "memory");
    else if (t + 2 < NT)
      asm volatile("s_waitcnt vmcnt(4)" ::: "memory");
    else
      asm volatile("s_waitcnt vmcnt(0)" ::: "memory");
    __builtin_amdgcn_s_barrier();
  }

#pragma unroll
  for (int mi = 0; mi < 8; ++mi) {
#pragma unroll
    for (int nj = 0; nj < 4; ++nj) {
      int n = n0 + wc * 64 + nj * 16 + fr;
      if (n < VOCABSZ) {
        int m = m0 + wr * 128 + mi * 16 + ks * 4;
#pragma unroll
        for (int r = 0; r < 4; ++r)
          C[(size_t)(m + r) * VOCABSZ + n] = acc[mi][nj][r];
      }
    }
  }
}

// ---------------------------------------------------------------- launch
extern "C" void kernel_launch(void* const* d_in, const int* in_sizes, int n_in,
                              void* d_out, int out_size, void* d_ws,
                              size_t ws_size, hipStream_t stream) {
  const int* tokens = (const int*)d_in[0];
  const int* tmask = (const int*)d_in[1];
  const float* embed = (const float*)d_in[2];
  const float* pos = (const float*)d_in[3];
  const float* wq = (const float*)d_in[4];
  const float* wk = (const float*)d_in[5];
  const float* wv = (const float*)d_in[6];
  const float* wo = (const float*)d_in[7];
  const float* ln1g = (const float*)d_in[8];
  const float* ln1b = (const float*)d_in[9];
  const float* ln2g = (const float*)d_in[10];
  const float* ln2b = (const float*)d_in[11];
  const float* fw1 = (const float*)d_in[12];
  const float* fb1 = (const float*)d_in[13];
  const float* fw2 = (const float*)d_in[14];
  const float* fb2 = (const float*)d_in[15];
  const float* lnfg = (const float*)d_in[16];
  const float* lnfb = (const float*)d_in[17];

  char* wp = (char*)d_ws;
  auto alloc = [&](size_t bytes) {
    void* p = wp;
    wp += (bytes + 255) & ~(size_t)255;
    return p;
  };
  float* h = (float*)alloc((size_t)BT * DMODEL * 4);
  float* part = (float*)alloc((size_t)4 * BT * DMODEL * 4);
  ushort* qb = (ushort*)alloc((size_t)BT * DMODEL * 2);
  ushort* kb = (ushort*)alloc((size_t)BT * DMODEL * 2);
  ushort* vt = (ushort*)alloc((size_t)NBH * DHEAD * SEQ * 2);
  ushort* xn = (ushort*)alloc((size_t)BT * DMODEL * 2);
  ushort* ab = (ushort*)alloc((size_t)BT * DMODEL * 2);
  ushort* ffb = (ushort*)alloc((size_t)BT * DFFN * 2);
  ushort* wqkv_b = (ushort*)alloc((size_t)NLAYER * 3 * DMODEL * DMODEL * 2);
  ushort* wo_b = (ushort*)alloc((size_t)NLAYER * DMODEL * DMODEL * 2);
  ushort* fw1_b = (ushort*)alloc((size_t)NLAYER * DFFN * DMODEL * 2);
  ushort* fw2_b = (ushort*)alloc((size_t)NLAYER * DMODEL * DFFN * 2);
  ushort* emb_b = (ushort*)alloc((size_t)VPAD * DMODEL * 2);

  const int per4 = DMODEL * DMODEL / 4;
  conv_qkv_kernel<<<(NLAYER * per4 + 255) / 256, 256, 0, stream>>>(wq, wqkv_b, 0);
  conv_qkv_kernel<<<(NLAYER * per4 + 255) / 256, 256, 0, stream>>>(wk, wqkv_b, per4);
  conv_qkv_kernel<<<(NLAYER * per4 + 255) / 256, 256, 0, stream>>>(wv, wqkv_b, 2 * per4);
  conv4_kernel<<<(NLAYER * per4 + 255) / 256, 256, 0, stream>>>(wo, wo_b, NLAYER * per4);
  const int nff4 = NLAYER * DFFN * DMODEL / 4;
  conv4_kernel<<<(nff4 + 255) / 256, 256, 0, stream>>>(fw1, fw1_b, nff4);
  conv4_kernel<<<(nff4 + 255) / 256, 256, 0, stream>>>(fw2, fw2_b, nff4);
  conv_embed_kernel<<<(VPAD * DMODEL / 4 + 255) / 256, 256, 0, stream>>>(embed, emb_b);

  embed_kernel<<<BT, 256, 0, stream>>>(tokens, embed, pos, h);

  const dim3 gqkv(3 * DMODEL / 128, BT / 128);
  const dim3 gff(DFFN / 128, BT / 128);
  const dim3 gwo(DMODEL / 128, BT / 128, 2);
  const dim3 gff2(DMODEL / 128, BT / 128, 4);

  for (int i = 0; i < NLAYER; ++i) {
    if (i == 0)
      ln_kernel<0, false><<<BT, 256, 0, stream>>>(
          h, nullptr, nullptr, ln1g + i * DMODEL, ln1b + i * DMODEL, xn);
    else
      ln_kernel<4, true><<<BT, 256, 0, stream>>>(
          h, part, fb2 + (i - 1) * DMODEL, ln1g + i * DMODEL,
          ln1b + i * DMODEL, xn);

    gemm_bf16_nt<true, false, false, false, false, false>
        <<<gqkv, 256, 0, stream>>>(
            xn, wqkv_b + (size_t)i * 3 * DMODEL * DMODEL, nullptr,
            tmask + i * DMODEL, nullptr, nullptr, nullptr, 0, qb, kb, vt, BT,
            DMODEL, 3 * DMODEL, DMODEL);

    fattn_kernel<<<dim3(SEQ / 64, NBH), 256, 0, stream>>>(qb, kb, vt, ab);

    gemm_bf16_nt<false, false, false, false, false, true>
        <<<gwo, 256, 0, stream>>>(
            ab, wo_b + (size_t)i * DMODEL * DMODEL, nullptr, nullptr, nullptr,
            part, nullptr, DMODEL, nullptr, nullptr, nullptr, BT, DMODEL,
            DMODEL, DMODEL / 2);

    ln_kernel<2, false><<<BT, 256, 0, stream>>>(
        h, part, nullptr, ln2g + i * DMODEL, ln2b + i * DMODEL, xn);

    gemm_bf16_nt<false, true, true, false, true, false>
        <<<gff, 256, 0, stream>>>(
            xn, fw1_b + (size_t)i * DFFN * DMODEL, fb1 + i * DFFN, nullptr,
            nullptr, nullptr, ffb, DFFN, nullptr, nullptr, nullptr, BT, DMODEL,
            DFFN, DMODEL);

    gemm_bf16_nt<false, false, false, false, false, true>
        <<<gff2, 256, 0, stream>>>(
            ffb, fw2_b + (size_t)i * DMODEL * DFFN, nullptr, nullptr, nullptr,
            part, nullptr, DMODEL, nullptr, nullptr, nullptr, BT, DFFN, DMODEL,
            DFFN / 4);
  }

  ln_kernel<4, true><<<BT, 256, 0, stream>>>(
      h, part, fb2 + (NLAYER - 1) * DMODEL, lnfg, lnfb, xn);

  gemm_lmhead<<<8 * (VPAD / 256), 512, 0, stream>>>(xn, emb_b, (float*)d_out);
}

// Round 8
// 927.239 us; speedup vs baseline: 7.9983x; 1.0156x over previous
//
#include <hip/hip_runtime.h>
#include <math.h>

#define VOCABSZ 50257
#define VPAD 50432
#define DMODEL 768
#define NHEAD 12
#define NLAYER 4
#define SEQ 1024
#define BATCH 2
#define DHEAD 64
#define DFFN 3072
#define BT (BATCH * SEQ)
#define NBH (BATCH * NHEAD)

typedef __attribute__((ext_vector_type(8))) short bf16x8;
typedef __attribute__((ext_vector_type(4))) float f32x4;

__device__ __forceinline__ ushort f2bf(float f) {
  uint u = __builtin_bit_cast(uint, f);
  u = (u + 0x7fffu + ((u >> 16) & 1u)) >> 16;
  return (ushort)u;
}

__device__ __forceinline__ void gl_lds16(const ushort* g, ushort* l) {
  __builtin_amdgcn_global_load_lds(
      (const __attribute__((address_space(1))) void*)g,
      (__attribute__((address_space(3))) void*)l, 16, 0, 0);
}

// ------------------------------------------------------------- conversions
__global__ __launch_bounds__(256) void conv4_kernel(
    const float* __restrict__ src, ushort* __restrict__ dst, int n4) {
  int i = blockIdx.x * 256 + threadIdx.x;
  if (i >= n4) return;
  float4 v = reinterpret_cast<const float4*>(src)[i];
  reinterpret_cast<ushort4*>(dst)[i] =
      make_ushort4(f2bf(v.x), f2bf(v.y), f2bf(v.z), f2bf(v.w));
}

__global__ __launch_bounds__(256) void conv_qkv_kernel(
    const float* __restrict__ src, ushort* __restrict__ dst, int qoff4) {
  const int per4 = DMODEL * DMODEL / 4;
  int i = blockIdx.x * 256 + threadIdx.x;
  if (i >= NLAYER * per4) return;
  int layer = i / per4, rem = i % per4;
  float4 v = reinterpret_cast<const float4*>(src)[i];
  reinterpret_cast<ushort4*>(dst)[(size_t)layer * (3 * per4) + qoff4 + rem] =
      make_ushort4(f2bf(v.x), f2bf(v.y), f2bf(v.z), f2bf(v.w));
}

__global__ __launch_bounds__(256) void conv_embed_kernel(
    const float* __restrict__ emb, ushort* __restrict__ dst) {
  int i = blockIdx.x * 256 + threadIdx.x;
  if (i >= VPAD * DMODEL / 4) return;
  int row = (i * 4) / DMODEL;
  ushort4 o = make_ushort4(0, 0, 0, 0);
  if (row < VOCABSZ) {
    float4 v = reinterpret_cast<const float4*>(emb)[i];
    o = make_ushort4(f2bf(v.x), f2bf(v.y), f2bf(v.z), f2bf(v.w));
  }
  reinterpret_cast<ushort4*>(dst)[i] = o;
}

// ---------------------------------------------------------------- embedding
__global__ __launch_bounds__(256) void embed_kernel(
    const int* __restrict__ tok, const float* __restrict__ emb,
    const float* __restrict__ pos, float* __restrict__ h) {
  int row = blockIdx.x;
  int l = row % SEQ;
  int t = tok[row];
  int tid = threadIdx.x;
#pragma unroll
  for (int j = 0; j < 3; ++j) {
    int c = tid + j * 256;
    h[(size_t)row * DMODEL + c] =
        emb[(size_t)t * DMODEL + c] + pos[(size_t)l * DMODEL + c];
  }
}

// --------------------------------------- layernorm (+ fused split-K reduce)
template <int KS, bool RBIAS>
__global__ __launch_bounds__(256) void ln_kernel(
    float* __restrict__ h, const float* __restrict__ part,
    const float* __restrict__ rb, const float* __restrict__ g,
    const float* __restrict__ bta, ushort* __restrict__ o) {
  __shared__ float red[8];
  int row = blockIdx.x;
  int tid = threadIdx.x;
  float* xr = h + (size_t)row * DMODEL;
  float v[3];
  float s = 0.f, sq = 0.f;
#pragma unroll
  for (int j = 0; j < 3; ++j) {
    int c = tid + j * 256;
    float a = xr[c];
    if (RBIAS) a += rb[c];
    if (KS > 0) {
#pragma unroll
      for (int z = 0; z < KS; ++z)
        a += part[(size_t)z * BT * DMODEL + (size_t)row * DMODEL + c];
      xr[c] = a;
    }
    v[j] = a;
    s += a;
    sq += a * a;
  }
#pragma unroll
  for (int off = 1; off < 64; off <<= 1) {
    s += __shfl_xor(s, off);
    sq += __shfl_xor(sq, off);
  }
  int wid = tid >> 6;
  if ((tid & 63) == 0) { red[wid * 2] = s; red[wid * 2 + 1] = sq; }
  __syncthreads();
  float S = red[0] + red[2] + red[4] + red[6];
  float SQ = red[1] + red[3] + red[5] + red[7];
  float mu = S * (1.0f / DMODEL);
  float var = SQ * (1.0f / DMODEL) - mu * mu;
  float r = rsqrtf(var + 1e-5f);
  ushort* orow = o + (size_t)row * DMODEL;
#pragma unroll
  for (int j = 0; j < 3; ++j) {
    int c = tid + j * 256;
    orow[c] = f2bf((v[j] - mu) * r * g[c] + bta[c]);
  }
}

// -------------------------------------------------------- flash attention
__global__ __launch_bounds__(256) void fattn_kernel(
    const ushort* __restrict__ q, const ushort* __restrict__ k,
    const ushort* __restrict__ vt, ushort* __restrict__ o) {
  __shared__ __align__(16) ushort Ks[64 * 64];
  __shared__ __align__(16) ushort Vs[64 * 64];
  __shared__ __align__(16) ushort Ps[4][16][80];
  const int z = blockIdx.y, b = z / NHEAD, hh = z % NHEAD;
  const int q0 = (gridDim.x - 1 - blockIdx.x) * 64;  // long blocks first
  const int tid = threadIdx.x, w = tid >> 6, l = tid & 63;
  const int fr = l & 15, ks = l >> 4;
  const int qrow = q0 + w * 16 + fr;
  const ushort* qp = q + (size_t)(b * SEQ + qrow) * DMODEL + hh * DHEAD;
  const bf16x8 qf0 = *reinterpret_cast<const bf16x8*>(qp + ks * 8);
  const bf16x8 qf1 = *reinterpret_cast<const bf16x8*>(qp + 32 + ks * 8);

  const int srow = w * 16 + (l >> 3);
  const int sslot = l & 7;

  f32x4 acc_o[4] = {};
  float mrun = -1e30f, lrun = 0.f;

  for (int k0 = 0; k0 <= q0; k0 += 64) {
#pragma unroll
    for (int c = 0; c < 2; ++c) {
      int r = srow + c * 8;
      int g = sslot ^ (r & 7);
      gl_lds16(k + (size_t)(b * SEQ + k0 + r) * DMODEL + hh * DHEAD + g * 8,
               Ks + (w * 16 + c * 8) * 64);
      gl_lds16(vt + (size_t)(z * 64 + r) * SEQ + k0 + g * 8,
               Vs + (w * 16 + c * 8) * 64);
    }
    __syncthreads();
    f32x4 acc_s[4] = {};
#pragma unroll
    for (int kstep = 0; kstep < 2; ++kstep) {
      const bf16x8 qf = kstep ? qf1 : qf0;
#pragma unroll
      for (int kb = 0; kb < 4; ++kb) {
        int ra = kb * 16 + fr;
        bf16x8 af = *reinterpret_cast<const bf16x8*>(
            Ks + ra * 64 + (((kstep * 4 + ks) ^ (ra & 7)) * 8));
        acc_s[kb] =
            __builtin_amdgcn_mfma_f32_16x16x32_bf16(af, qf, acc_s[kb], 0, 0, 0);
      }
    }
    const bool diag = (k0 == q0);
    float pm = -1e30f;
    float sv[4][4];
#pragma unroll
    for (int kb = 0; kb < 4; ++kb)
#pragma unroll
      for (int r = 0; r < 4; ++r) {
        float s = acc_s[kb][r];
        if (diag && (k0 + kb * 16 + ks * 4 + r > qrow)) s = -1e30f;
        sv[kb][r] = s;
        pm = fmaxf(pm, s);
      }
    pm = fmaxf(pm, __shfl_xor(pm, 16));
    pm = fmaxf(pm, __shfl_xor(pm, 32));
    float mnew = fmaxf(mrun, pm);
    float scale = __expf(mrun - mnew);
    float psum = 0.f;
#pragma unroll
    for (int kb = 0; kb < 4; ++kb) {
      float p0 = __expf(sv[kb][0] - mnew);
      float p1 = __expf(sv[kb][1] - mnew);
      float p2 = __expf(sv[kb][2] - mnew);
      float p3 = __expf(sv[kb][3] - mnew);
      psum += (p0 + p1) + (p2 + p3);
      *reinterpret_cast<ushort4*>(&Ps[w][fr][kb * 16 + ks * 4]) =
          make_ushort4(f2bf(p0), f2bf(p1), f2bf(p2), f2bf(p3));
    }
    psum += __shfl_xor(psum, 16);
    psum += __shfl_xor(psum, 32);
    lrun = lrun * scale + psum;
    mrun = mnew;
#pragma unroll
    for (int db = 0; db < 4; ++db) acc_o[db] *= scale;
#pragma unroll
    for (int kstep = 0; kstep < 2; ++kstep) {
      bf16x8 pf =
          *reinterpret_cast<const bf16x8*>(&Ps[w][fr][kstep * 32 + ks * 8]);
#pragma unroll
      for (int db = 0; db < 4; ++db) {
        int rd = db * 16 + fr;
        bf16x8 vf = *reinterpret_cast<const bf16x8*>(
            Vs + rd * 64 + (((kstep * 4 + ks) ^ (rd & 7)) * 8));
        acc_o[db] =
            __builtin_amdgcn_mfma_f32_16x16x32_bf16(vf, pf, acc_o[db], 0, 0, 0);
      }
    }
    __syncthreads();
  }
  float rinv = 1.0f / lrun;
#pragma unroll
  for (int db = 0; db < 4; ++db) {
    ushort4 o4 =
        make_ushort4(f2bf(acc_o[db][0] * rinv), f2bf(acc_o[db][1] * rinv),
                     f2bf(acc_o[db][2] * rinv), f2bf(acc_o[db][3] * rinv));
    *reinterpret_cast<ushort4*>(o + (size_t)(b * SEQ + qrow) * DMODEL +
                                hh * DHEAD + db * 16 + ks * 4) = o4;
  }
}

// ------------------------------------------------------- bf16 MFMA NT GEMM
// 128x128 tile, BK=32, 2-deep LDS ring with COUNTED vmcnt gate (T4):
// stage t+1, s_waitcnt vmcnt(4) [t resident, t+1 in flight], s_barrier,
// compute t, s_barrier. High residency (5 blocks/CU by LDS) + T4 overlap.
// SWZ: XCD-chunked 1-D grid (m-fast). PART: split-K partials via blockIdx.z.
template <bool QKV, bool BIAS, bool GELU, bool RES, bool OUTBF, bool SWZ,
          bool PART>
__global__ __launch_bounds__(256) void gemm_bf16_nt(
    const ushort* __restrict__ A, const ushort* __restrict__ B,
    const float* __restrict__ bias, const int* __restrict__ tmask,
    const float* __restrict__ res, float* __restrict__ Cf,
    ushort* __restrict__ Cb, int ldc, ushort* __restrict__ qb,
    ushort* __restrict__ kb, ushort* __restrict__ vt, int M, int K, int Nreal,
    int kchunk) {
  __shared__ __align__(16) ushort As[2][128 * 32];
  __shared__ __align__(16) ushort Bs[2][128 * 32];
  int bnx, bmy;
  if (SWZ) {
    int bid = blockIdx.x;
    int chunk = gridDim.x >> 3;  // grid must be multiple of 8
    int wgid = (bid & 7) * chunk + (bid >> 3);
    int mb = M >> 7;
    bmy = wgid % mb;  // m fast -> B-panel reuse within XCD
    bnx = wgid / mb;
  } else {
    bnx = blockIdx.x;
    bmy = blockIdx.y;
  }
  const int m0 = bmy * 128, n0 = bnx * 128;
  const int kbeg = PART ? blockIdx.z * kchunk : 0;
  const int kend = PART ? kbeg + kchunk : K;
  if (PART) Cf += (size_t)blockIdx.z * M * ldc;
  const int tid = threadIdx.x;
  const int w = tid >> 6, l = tid & 63;
  const int wr = w >> 1, wc = w & 1;
  const int fr = l & 15, ks = l >> 4;

  const int seg0 = w * 2, seg1 = w * 2 + 1;
  const int srow0 = seg0 * 16 + (l >> 2);
  const int srow1 = seg1 * 16 + (l >> 2);
  const int koff0 = (((l & 3) ^ ((srow0 >> 1) & 3))) * 8;
  const int koff1 = (((l & 3) ^ ((srow1 >> 1) & 3))) * 8;
  const ushort* A0 = A + (size_t)(m0 + srow0) * K + koff0;
  const ushort* A1 = A + (size_t)(m0 + srow1) * K + koff1;
  const ushort* B0 = B + (size_t)(n0 + srow0) * K + koff0;
  const ushort* B1 = B + (size_t)(n0 + srow1) * K + koff1;

  int aoff[4], boff[4];
#pragma unroll
  for (int i = 0; i < 4; ++i) {
    int ra = wr * 64 + i * 16 + fr;
    aoff[i] = ra * 32 + ((ks ^ ((ra >> 1) & 3)) * 8);
    int rb = wc * 64 + i * 16 + fr;
    boff[i] = rb * 32 + ((ks ^ ((rb >> 1) & 3)) * 8);
  }

  // prologue: stage tile 0 into buffer 0 (no wait yet)
  gl_lds16(A0 + kbeg, &As[0][seg0 * 512]);
  gl_lds16(A1 + kbeg, &As[0][seg1 * 512]);
  gl_lds16(B0 + kbeg, &Bs[0][seg0 * 512]);
  gl_lds16(B1 + kbeg, &Bs[0][seg1 * 512]);

  f32x4 acc[4][4] = {};
  int cur = 0;
  for (int k0 = kbeg; k0 < kend; k0 += 32) {
    const int nxt = k0 + 32;
    if (nxt < kend) {  // stage t+1, then gate on t only (t+1 stays in flight)
      gl_lds16(A0 + nxt, &As[cur ^ 1][seg0 * 512]);
      gl_lds16(A1 + nxt, &As[cur ^ 1][seg1 * 512]);
      gl_lds16(B0 + nxt, &Bs[cur ^ 1][seg0 * 512]);
      gl_lds16(B1 + nxt, &Bs[cur ^ 1][seg1 * 512]);
      asm volatile("s_waitcnt vmcnt(4)" ::: "memory");
    } else {
      asm volatile("s_waitcnt vmcnt(0)" ::: "memory");
    }
    __builtin_amdgcn_s_barrier();
    __builtin_amdgcn_sched_barrier(0);
    bf16x8 af[4], bfr[4];
#pragma unroll
    for (int i = 0; i < 4; ++i)
      af[i] = *reinterpret_cast<const bf16x8*>(&As[cur][aoff[i]]);
#pragma unroll
    for (int i = 0; i < 4; ++i)
      bfr[i] = *reinterpret_cast<const bf16x8*>(&Bs[cur][boff[i]]);
#pragma unroll
    for (int mi = 0; mi < 4; ++mi)
#pragma unroll
      for (int nj = 0; nj < 4; ++nj)
        acc[mi][nj] = __builtin_amdgcn_mfma_f32_16x16x32_bf16(
            af[mi], bfr[nj], acc[mi][nj], 0, 0, 0);
    __builtin_amdgcn_sched_barrier(0);
    __builtin_amdgcn_s_barrier();  // readers done before buf[cur] is restaged
    cur ^= 1;
  }

#pragma unroll
  for (int mi = 0; mi < 4; ++mi) {
#pragma unroll
    for (int nj = 0; nj < 4; ++nj) {
      int n = n0 + wc * 64 + nj * 16 + fr;
      if (n < Nreal) {
        if (PART) {
#pragma unroll
          for (int r = 0; r < 4; ++r) {
            int m = m0 + wr * 64 + mi * 16 + ks * 4 + r;
            Cf[(size_t)m * ldc + n] = acc[mi][nj][r];
          }
        } else if (QKV) {
          if (n < DMODEL) {
            float sc = (1.0f - 0.5f * (float)tmask[n]) * 0.125f;
#pragma unroll
            for (int r = 0; r < 4; ++r) {
              int m = m0 + wr * 64 + mi * 16 + ks * 4 + r;
              qb[(size_t)m * DMODEL + n] = f2bf(acc[mi][nj][r] * sc);
            }
          } else if (n < 2 * DMODEL) {
#pragma unroll
            for (int r = 0; r < 4; ++r) {
              int m = m0 + wr * 64 + mi * 16 + ks * 4 + r;
              kb[(size_t)m * DMODEL + (n - DMODEL)] = f2bf(acc[mi][nj][r]);
            }
          } else {
            // V written head-transposed: vt[(b*H+h)*64+d][key]
            int d = n - 2 * DMODEL;
            int key = (m0 & (SEQ - 1)) + wr * 64 + mi * 16 + ks * 4;
            size_t zr = (size_t)((m0 >> 10) * NHEAD + (d >> 6)) * 64 + (d & 63);
            ushort4 p4 = make_ushort4(
                f2bf(acc[mi][nj][0]), f2bf(acc[mi][nj][1]),
                f2bf(acc[mi][nj][2]), f2bf(acc[mi][nj][3]));
            *reinterpret_cast<ushort4*>(vt + zr * SEQ + key) = p4;
          }
        } else {
#pragma unroll
          for (int r = 0; r < 4; ++r) {
            int m = m0 + wr * 64 + mi * 16 + ks * 4 + r;
            float v = acc[mi][nj][r];
            if (BIAS) v += bias[n];
            if (GELU) v = 0.5f * v * (1.0f + erff(v * 0.70710678118f));
            if (RES) v += res[(size_t)m * ldc + n];
            if (OUTBF)
              Cb[(size_t)m * ldc + n] = f2bf(v);
            else
              Cf[(size_t)m * ldc + n] = v;
          }
        }
      }
    }
  }
}

// ---------------------------------------------------------------- launch
extern "C" void kernel_launch(void* const* d_in, const int* in_sizes, int n_in,
                              void* d_out, int out_size, void* d_ws,
                              size_t ws_size, hipStream_t stream) {
  const int* tokens = (const int*)d_in[0];
  const int* tmask = (const int*)d_in[1];
  const float* embed = (const float*)d_in[2];
  const float* pos = (const float*)d_in[3];
  const float* wq = (const float*)d_in[4];
  const float* wk = (const float*)d_in[5];
  const float* wv = (const float*)d_in[6];
  const float* wo = (const float*)d_in[7];
  const float* ln1g = (const float*)d_in[8];
  const float* ln1b = (const float*)d_in[9];
  const float* ln2g = (const float*)d_in[10];
  const float* ln2b = (const float*)d_in[11];
  const float* fw1 = (const float*)d_in[12];
  const float* fb1 = (const float*)d_in[13];
  const float* fw2 = (const float*)d_in[14];
  const float* fb2 = (const float*)d_in[15];
  const float* lnfg = (const float*)d_in[16];
  const float* lnfb = (const float*)d_in[17];

  char* wp = (char*)d_ws;
  auto alloc = [&](size_t bytes) {
    void* p = wp;
    wp += (bytes + 255) & ~(size_t)255;
    return p;
  };
  float* h = (float*)alloc((size_t)BT * DMODEL * 4);
  float* part = (float*)alloc((size_t)4 * BT * DMODEL * 4);
  ushort* qb = (ushort*)alloc((size_t)BT * DMODEL * 2);
  ushort* kb = (ushort*)alloc((size_t)BT * DMODEL * 2);
  ushort* vt = (ushort*)alloc((size_t)NBH * DHEAD * SEQ * 2);
  ushort* xn = (ushort*)alloc((size_t)BT * DMODEL * 2);
  ushort* ab = (ushort*)alloc((size_t)BT * DMODEL * 2);
  ushort* ffb = (ushort*)alloc((size_t)BT * DFFN * 2);
  ushort* wqkv_b = (ushort*)alloc((size_t)NLAYER * 3 * DMODEL * DMODEL * 2);
  ushort* wo_b = (ushort*)alloc((size_t)NLAYER * DMODEL * DMODEL * 2);
  ushort* fw1_b = (ushort*)alloc((size_t)NLAYER * DFFN * DMODEL * 2);
  ushort* fw2_b = (ushort*)alloc((size_t)NLAYER * DMODEL * DFFN * 2);
  ushort* emb_b = (ushort*)alloc((size_t)VPAD * DMODEL * 2);

  const int per4 = DMODEL * DMODEL / 4;
  conv_qkv_kernel<<<(NLAYER * per4 + 255) / 256, 256, 0, stream>>>(wq, wqkv_b, 0);
  conv_qkv_kernel<<<(NLAYER * per4 + 255) / 256, 256, 0, stream>>>(wk, wqkv_b, per4);
  conv_qkv_kernel<<<(NLAYER * per4 + 255) / 256, 256, 0, stream>>>(wv, wqkv_b, 2 * per4);
  conv4_kernel<<<(NLAYER * per4 + 255) / 256, 256, 0, stream>>>(wo, wo_b, NLAYER * per4);
  const int nff4 = NLAYER * DFFN * DMODEL / 4;
  conv4_kernel<<<(nff4 + 255) / 256, 256, 0, stream>>>(fw1, fw1_b, nff4);
  conv4_kernel<<<(nff4 + 255) / 256, 256, 0, stream>>>(fw2, fw2_b, nff4);
  conv_embed_kernel<<<(VPAD * DMODEL / 4 + 255) / 256, 256, 0, stream>>>(embed, emb_b);

  embed_kernel<<<BT, 256, 0, stream>>>(tokens, embed, pos, h);

  const dim3 gqkv(3 * DMODEL / 128, BT / 128);
  const dim3 gff(DFFN / 128, BT / 128);
  const dim3 gwo(DMODEL / 128, BT / 128, 2);
  const dim3 gff2(DMODEL / 128, BT / 128, 4);
  const int gv = (BT / 128) * (VPAD / 128);  // 6304, multiple of 8

  for (int i = 0; i < NLAYER; ++i) {
    if (i == 0)
      ln_kernel<0, false><<<BT, 256, 0, stream>>>(
          h, nullptr, nullptr, ln1g + i * DMODEL, ln1b + i * DMODEL, xn);
    else
      ln_kernel<4, true><<<BT, 256, 0, stream>>>(
          h, part, fb2 + (i - 1) * DMODEL, ln1g + i * DMODEL,
          ln1b + i * DMODEL, xn);

    gemm_bf16_nt<true, false, false, false, false, false, false>
        <<<gqkv, 256, 0, stream>>>(
            xn, wqkv_b + (size_t)i * 3 * DMODEL * DMODEL, nullptr,
            tmask + i * DMODEL, nullptr, nullptr, nullptr, 0, qb, kb, vt, BT,
            DMODEL, 3 * DMODEL, DMODEL);

    fattn_kernel<<<dim3(SEQ / 64, NBH), 256, 0, stream>>>(qb, kb, vt, ab);

    gemm_bf16_nt<false, false, false, false, false, false, true>
        <<<gwo, 256, 0, stream>>>(
            ab, wo_b + (size_t)i * DMODEL * DMODEL, nullptr, nullptr, nullptr,
            part, nullptr, DMODEL, nullptr, nullptr, nullptr, BT, DMODEL,
            DMODEL, DMODEL / 2);

    ln_kernel<2, false><<<BT, 256, 0, stream>>>(
        h, part, nullptr, ln2g + i * DMODEL, ln2b + i * DMODEL, xn);

    gemm_bf16_nt<false, true, true, false, true, false, false>
        <<<gff, 256, 0, stream>>>(
            xn, fw1_b + (size_t)i * DFFN * DMODEL, fb1 + i * DFFN, nullptr,
            nullptr, nullptr, ffb, DFFN, nullptr, nullptr, nullptr, BT, DMODEL,
            DFFN, DMODEL);

    gemm_bf16_nt<false, false, false, false, false, false, true>
        <<<gff2, 256, 0, stream>>>(
            ffb, fw2_b + (size_t)i * DMODEL * DFFN, nullptr, nullptr, nullptr,
            part, nullptr, DMODEL, nullptr, nullptr, nullptr, BT, DFFN, DMODEL,
            DFFN / 4);
  }

  ln_kernel<4, true><<<BT, 256, 0, stream>>>(
      h, part, fb2 + (NLAYER - 1) * DMODEL, lnfg, lnfb, xn);

  gemm_bf16_nt<false, false, false, false, false, true, false>
      <<<gv, 256, 0, stream>>>(
          xn, emb_b, nullptr, nullptr, nullptr, (float*)d_out, nullptr,
          VOCABSZ, nullptr, nullptr, nullptr, BT, DMODEL, VOCABSZ, DMODEL);
}